// Round 2
// baseline (4548.849 us; speedup 1.0000x reference)
//
#include <hip/hip_runtime.h>
#include <math.h>

#define BQ 1024
#define TT 128
#define DD 128
#define HH 256
#define BB 16           // batch rows per block
#define NW 16           // waves per block
#define NTH (NW*64)

typedef float f32x2 __attribute__((ext_vector_type(2)));
typedef float f32x4 __attribute__((ext_vector_type(4)));
typedef __bf16 bf16x8 __attribute__((ext_vector_type(8)));
typedef unsigned short u16x2 __attribute__((ext_vector_type(2)));
typedef unsigned short u16x8 __attribute__((ext_vector_type(8)));

// packed-weight tiles: each tile = one MFMA B-fragment set = 64 lanes x 8 bf16 = 1024 B
// B_hw[k = kb*32 + (lane>>4)*8 + e][n = nt*16 + (lane&15)] = W[n][k]
#define TW_DEC   0      // W_decay  N=256 K=128 : 16*4  = 64 tiles
#define TW_HIST  64     // W_hist   N=128 K=256 : 8*8   = 64
#define TW_WV    128    // Wv*off   N=128 K=128 : 8*4   = 32
#define TW_WR    160    // Wr*off   N=128 K=128 : 32
#define TW_WIH   192    // W_ih     N=768 K=256 : 48*8  = 384
#define TW_WHH   576    // W_hh     N=768 K=256 : 384
#define TW_TOTAL 960

__device__ __forceinline__ unsigned short f2bf(float f){
  union { float f; unsigned u; } v; v.f = f;
  unsigned r = v.u + 0x7FFFu + ((v.u >> 16) & 1u);
  return (unsigned short)(r >> 16);
}
__device__ __forceinline__ float bf2f(unsigned short u){
  union { unsigned u; float f; } v; v.u = ((unsigned)u) << 16; return v.f;
}
__device__ __forceinline__ float sigm(float v){ return 1.f/(1.f + __expf(-v)); }

__device__ __forceinline__ bf16x8 ldB(const unsigned short* wbf, int tile, int lane){
  return *(const bf16x8*)(wbf + (size_t)tile*512 + lane*8);
}
__device__ __forceinline__ f32x4 mfma16(bf16x8 a, bf16x8 b, f32x4 c){
  return __builtin_amdgcn_mfma_f32_16x16x32_bf16(a, b, c, 0, 0, 0);
}

// ---------------- pack weights (f32 row-major [N][K] -> bf16 B-fragment stream) --------
__global__ void pack_weights(const float* Wdec, const float* Whist, const float* Wv,
                             const float* Wr, const float* Wih, const float* Whh,
                             unsigned short* wbf){
  int gt = blockIdx.x * 4 + (threadIdx.x >> 6);
  int lane = threadIdx.x & 63;
  if (gt >= TW_TOTAL) return;
  const float* src; int K, tl; int dm = 0;
  if (gt < TW_HIST)      { src = Wdec;  K = DD;  tl = gt; }
  else if (gt < TW_WV)   { src = Whist; K = HH;  tl = gt - TW_HIST; }
  else if (gt < TW_WR)   { src = Wv;    K = DD;  tl = gt - TW_WV;  dm = 1; }
  else if (gt < TW_WIH)  { src = Wr;    K = DD;  tl = gt - TW_WR;  dm = 1; }
  else if (gt < TW_WHH)  { src = Wih;   K = 256; tl = gt - TW_WIH; }
  else                   { src = Whh;   K = 256; tl = gt - TW_WHH; }
  int nkb = K >> 5;
  int nt = tl / nkb, kb = tl - nt*nkb;
  int n  = nt*16 + (lane & 15);
  int k0 = kb*32 + (lane >> 4)*8;
  u16x8 pk;
  #pragma unroll
  for (int e = 0; e < 8; ++e){
    int k = k0 + e;
    float wv = src[(size_t)n*K + k];
    if (dm && n == k) wv = 0.f;   // zero-diagonal feature-regression mask
    pk[e] = f2bf(wv);
  }
  *(u16x8*)(wbf + (size_t)gt*512 + lane*8) = pk;
}

// ---------------- per-step mask sums M_t, zero loss numerators ----------------
__global__ void msum_kernel(const float* m, float* wsf){
  int t = blockIdx.x;
  float s = 0.f;
  for (int i = threadIdx.x; i < BQ*DD; i += 256){
    int b = i >> 7, d0 = i & 127;
    s += m[((size_t)b*TT + t)*DD + d0];
  }
  #pragma unroll
  for (int off = 32; off >= 1; off >>= 1) s += __shfl_down(s, off);
  __shared__ float ps[4];
  if ((threadIdx.x & 63) == 0) ps[threadIdx.x >> 6] = s;
  __syncthreads();
  if (threadIdx.x == 0){
    wsf[128 + t] = ps[0] + ps[1] + ps[2] + ps[3];
    wsf[t] = 0.f;
  }
}

// ---------------- final loss reduction ----------------
__global__ void loss_final(const float* wsf, float* out_loss){
  __shared__ float ps[TT];
  int t = threadIdx.x;
  ps[t] = wsf[t] / (wsf[128 + t] + 1e-5f);
  __syncthreads();
  if (t == 0){ float s = 0.f; for (int i = 0; i < TT; ++i) s += ps[i]; *out_loss = s; }
}

// ---------------- the recurrent scan ----------------
// LDS layout (bytes). bf16 tiles are row-major with XOR swizzle: byte ^= (row&7)<<4
#define L_H    0        // h'  [16][256] bf16, stride 512
#define L_D    8192     // d_t [16][128] bf16, stride 256
#define L_XB   12288    // xbar
#define L_M    16384    // m
#define L_XR   20480    // x_r
#define L_XI   24576    // x_imp
#define L_XF   28672    // x   [16][128] f32, linear, stride 512
#define L_XU   36864    // xu  [16][128] f32, linear
#define L_RED  45056    // 8 f32
#define L_HF   45088    // h final [16][256] f32 (post-loop only)
#define L_PS   61472    // 256 f32
#define L_TOT  62496

__global__ __launch_bounds__(NTH, 4) void scan_kernel(
    const float* __restrict__ x, const float* __restrict__ xhat,
    const float* __restrict__ m, const float* __restrict__ dly,
    const float* __restrict__ b_dec, const float* __restrict__ b_hist,
    const float* __restrict__ bv, const float* __restrict__ br,
    const float* __restrict__ conv_w, const float* __restrict__ conv_b,
    const float* __restrict__ b_ih, const float* __restrict__ b_hh,
    const float* __restrict__ W_out, const float* __restrict__ b_out,
    const unsigned short* __restrict__ wbf, float* __restrict__ lossN,
    float* __restrict__ out_ximp, float* __restrict__ out_y,
    float* __restrict__ out_ys, float* __restrict__ out_xu,
    float* __restrict__ out_xrs)
{
  __shared__ __align__(16) char lds[L_TOT];
  const int tid  = threadIdx.x;
  const int w    = tid >> 6;      // wave 0..15, owns h-cols [16w,16w+16)
  const int lane = tid & 63;
  const int lr   = lane & 15;
  const int lg   = lane >> 4;
  const int b0   = blockIdx.x * BB;
  const int colH = w*16 + lr;                 // h-col this wave/lane owns
  const int colDa = (w < 8) ? (w*16 + lr) : 0;      // D-col (xh/xr/ximp path, waves 0-7)
  const int colDb = (w >= 8) ? ((w-8)*16 + lr) : 0; // D-col (xu path, waves 8-15)

  const float bdec_v = b_dec[colH];
  const float bhist_v = (w < 8) ? b_hist[colDa] : 0.f;
  const float br_v    = (w < 8) ? br[colDa] : 0.f;
  const float bv_v    = (w >= 8) ? bv[colDb] : 0.f;
  float bihv[3], bhhv[3];
  #pragma unroll
  for (int g = 0; g < 3; ++g){
    bihv[g] = b_ih[g*256 + colH];
    bhhv[g] = b_hh[g*256 + colH];
  }
  const float cw0 = conv_w[0], cw1 = conv_w[1], cbv = conv_b[0];
  const f32x4 z4 = {0.f, 0.f, 0.f, 0.f};

  // h state in registers: hst[r] = h[row=lg*4+r][col=colH]
  float hst[4] = {0.f, 0.f, 0.f, 0.f};

  // staging mapping: each thread stages 2 floats of one row
  const int srow = tid >> 6;      // 0..15
  const int sc2  = (tid & 63)*2;  // float index 0,2,..,126
  const int sboff = (sc2*2) ^ ((srow & 7) << 4);  // bf16 byte offset, swizzled

  float* xlds  = (float*)(lds + L_XF);
  float* xulds = (float*)(lds + L_XU);
  float* red   = (float*)(lds + L_RED);

  for (int t = 0; t < TT; ++t){
    // ---- stage x/xbar/m/d tile for this step into LDS ----
    {
      size_t gofs = ((size_t)(b0 + srow)*TT + t)*DD + sc2;
      f32x2 xv = __builtin_nontemporal_load((const f32x2*)(x    + gofs));
      f32x2 hv = __builtin_nontemporal_load((const f32x2*)(xhat + gofs));
      f32x2 mv = __builtin_nontemporal_load((const f32x2*)(m    + gofs));
      f32x2 dv = __builtin_nontemporal_load((const f32x2*)(dly  + gofs));
      u16x2 pxb, pm, pd;
      #pragma unroll
      for (int e = 0; e < 2; ++e){
        pxb[e] = f2bf(mv[e]*xv[e] + (1.f - mv[e])*hv[e]);
        pm[e]  = f2bf(mv[e]);   // m is exactly 0/1 -> exact in bf16
        pd[e]  = f2bf(dv[e]);
      }
      *(f32x2*)(xlds + srow*128 + sc2) = xv;
      *(u16x2*)(lds + L_XB + srow*256 + sboff) = pxb;
      *(u16x2*)(lds + L_M  + srow*256 + sboff) = pm;
      *(u16x2*)(lds + L_D  + srow*256 + sboff) = pd;
    }
    __syncthreads();   // B1

    // ---- P0: gamma = exp(-relu(d @ Wdec^T + b)); h' = h * gamma; write h' to LDS ----
    {
      bf16x8 df[4];
      #pragma unroll
      for (int kb = 0; kb < 4; ++kb)
        df[kb] = *(const bf16x8*)(lds + L_D + lr*256 + ((kb*64 + lg*16) ^ ((lr & 7) << 4)));
      f32x4 ga = z4;
      #pragma unroll
      for (int kb = 0; kb < 4; ++kb)
        ga = mfma16(df[kb], ldB(wbf, TW_DEC + w*4 + kb, lane), ga);
      #pragma unroll
      for (int r = 0; r < 4; ++r){
        hst[r] *= __expf(-fmaxf(ga[r] + bdec_v, 0.f));
        int row = lg*4 + r;
        *(unsigned short*)(lds + L_H + row*512 + ((colH*2) ^ ((row & 7) << 4))) = f2bf(hst[r]);
      }
    }
    __syncthreads();   // B2

    // ---- P1: gh = h'@W_hh^T (all waves); xh = h'@W_hist^T (w<8); xu = xbar@Wv^T (w>=8) ----
    f32x4 gh[3];
    {
      bf16x8 hf[8];
      #pragma unroll
      for (int kb = 0; kb < 8; ++kb)
        hf[kb] = *(const bf16x8*)(lds + L_H + lr*512 + ((kb*64 + lg*16) ^ ((lr & 7) << 4)));
      #pragma unroll
      for (int g = 0; g < 3; ++g){
        gh[g] = z4;
        #pragma unroll
        for (int kb = 0; kb < 8; ++kb)
          gh[g] = mfma16(hf[kb], ldB(wbf, TW_WHH + (g*16 + w)*8 + kb, lane), gh[g]);
      }
      if (w < 8){
        f32x4 xh = z4;
        #pragma unroll
        for (int kb = 0; kb < 8; ++kb)
          xh = mfma16(hf[kb], ldB(wbf, TW_HIST + w*8 + kb, lane), xh);
        // x_r = m*x + (1-m)*(x_h + b_hist) -> LDS bf16
        #pragma unroll
        for (int r = 0; r < 4; ++r){
          int row = lg*4 + r;
          float mv = bf2f(*(const unsigned short*)(lds + L_M + row*256 + ((colDa*2) ^ ((row & 7) << 4))));
          float xv = xlds[row*128 + colDa];
          float xrin = mv*xv + (1.f - mv)*(xh[r] + bhist_v);
          *(unsigned short*)(lds + L_XR + row*256 + ((colDa*2) ^ ((row & 7) << 4))) = f2bf(xrin);
        }
      } else {
        bf16x8 xb[4];
        #pragma unroll
        for (int kb = 0; kb < 4; ++kb)
          xb[kb] = *(const bf16x8*)(lds + L_XB + lr*256 + ((kb*64 + lg*16) ^ ((lr & 7) << 4)));
        f32x4 xu = z4;
        #pragma unroll
        for (int kb = 0; kb < 4; ++kb)
          xu = mfma16(xb[kb], ldB(wbf, TW_WV + (w-8)*4 + kb, lane), xu);
        #pragma unroll
        for (int r = 0; r < 4; ++r){
          int row = lg*4 + r;
          float xuv = xu[r] + bv_v;
          xulds[row*128 + colDb] = xuv;
          size_t go = ((size_t)(b0 + row)*TT + t)*DD + colDb;
          __builtin_nontemporal_store(xuv, out_xu + go);
        }
      }
    }
    __syncthreads();   // B3

    // ---- P2 (w<8): xr = x_r@Wr^T + br ; outputs ; loss partial ; x_imp -> LDS ----
    float lpart = 0.f;
    if (w < 8){
      bf16x8 xrf[4];
      #pragma unroll
      for (int kb = 0; kb < 4; ++kb)
        xrf[kb] = *(const bf16x8*)(lds + L_XR + lr*256 + ((kb*64 + lg*16) ^ ((lr & 7) << 4)));
      f32x4 xrac = z4;
      #pragma unroll
      for (int kb = 0; kb < 4; ++kb)
        xrac = mfma16(xrf[kb], ldB(wbf, TW_WR + w*4 + kb, lane), xrac);
      #pragma unroll
      for (int r = 0; r < 4; ++r){
        int row = lg*4 + r;
        size_t go = ((size_t)(b0 + row)*TT + t)*DD + colDa;
        float xrv = xrac[r] + br_v;
        float xuv = xulds[row*128 + colDa];
        float mv = bf2f(*(const unsigned short*)(lds + L_M + row*256 + ((colDa*2) ^ ((row & 7) << 4))));
        float xv = xlds[row*128 + colDa];
        __builtin_nontemporal_store(xrv, out_xrs + go);
        float xc = cw0*xuv + cw1*xrv + cbv;
        lpart += fabsf(xv - xc)*mv;
        float xi = mv*xv + (1.f - mv)*xc;
        __builtin_nontemporal_store(xi, out_ximp + go);
        *(unsigned short*)(lds + L_XI + row*256 + ((colDa*2) ^ ((row & 7) << 4))) = f2bf(xi);
      }
      #pragma unroll
      for (int off = 32; off >= 1; off >>= 1) lpart += __shfl_down(lpart, off);
      if (lane == 0) red[w] = lpart;
    }
    __syncthreads();   // B4

    // ---- P3: gi = [x_imp, m]@W_ih^T ; gates ; h update ----
    {
      bf16x8 gif[8];
      #pragma unroll
      for (int kb = 0; kb < 4; ++kb)
        gif[kb] = *(const bf16x8*)(lds + L_XI + lr*256 + ((kb*64 + lg*16) ^ ((lr & 7) << 4)));
      #pragma unroll
      for (int kb = 0; kb < 4; ++kb)
        gif[4+kb] = *(const bf16x8*)(lds + L_M + lr*256 + ((kb*64 + lg*16) ^ ((lr & 7) << 4)));
      f32x4 gi[3];
      #pragma unroll
      for (int g = 0; g < 3; ++g){
        gi[g] = z4;
        #pragma unroll
        for (int kb = 0; kb < 8; ++kb)
          gi[g] = mfma16(gif[kb], ldB(wbf, TW_WIH + (g*16 + w)*8 + kb, lane), gi[g]);
      }
      #pragma unroll
      for (int r = 0; r < 4; ++r){
        float rr = sigm(gi[0][r] + bihv[0] + gh[0][r] + bhhv[0]);
        float zz = sigm(gi[1][r] + bihv[1] + gh[1][r] + bhhv[1]);
        float nn = tanhf(gi[2][r] + bihv[2] + rr*(gh[2][r] + bhhv[2]));
        hst[r] = (1.f - zz)*nn + zz*hst[r];
      }
      if (tid == 0){
        float s = 0.f;
        #pragma unroll
        for (int i = 0; i < 8; ++i) s += red[i];
        atomicAdd(&lossN[t], s);
      }
    }
    __syncthreads();   // B5 (protect LDS before next stage)
  }

  // ---- epilogue: y_out = h_fin @ W_out^T + b_out ; y_score = sigmoid ----
  float* hfin = (float*)(lds + L_HF);
  #pragma unroll
  for (int r = 0; r < 4; ++r)
    hfin[(lg*4 + r)*HH + colH] = hst[r];
  __syncthreads();
  float* psum = (float*)(lds + L_PS);
  if (tid < 256){
    int row = tid >> 4, seg = tid & 15;
    float p = 0.f;
    #pragma unroll
    for (int c = 0; c < 16; ++c) p += hfin[row*HH + seg*16 + c]*W_out[seg*16 + c];
    psum[tid] = p;
  }
  __syncthreads();
  if (tid < 16){
    float yv = b_out[0];
    #pragma unroll
    for (int i = 0; i < 16; ++i) yv += psum[tid*16 + i];
    out_y[b0 + tid] = yv;
    out_ys[b0 + tid] = sigm(yv);
  }
}

extern "C" void kernel_launch(void* const* d_in, const int* in_sizes, int n_in,
                              void* d_out, int out_size, void* d_ws, size_t ws_size,
                              hipStream_t stream){
  const float* x     = (const float*)d_in[0];
  const float* xhat  = (const float*)d_in[1];
  // d_in[2] = u (unused by reference)
  const float* m     = (const float*)d_in[3];
  const float* dly   = (const float*)d_in[4];
  const float* Wdec  = (const float*)d_in[5];
  const float* b_dec = (const float*)d_in[6];
  const float* Whist = (const float*)d_in[7];
  const float* b_hist= (const float*)d_in[8];
  const float* Wv    = (const float*)d_in[9];
  const float* bvv   = (const float*)d_in[10];
  const float* Wr    = (const float*)d_in[11];
  const float* brr   = (const float*)d_in[12];
  const float* convw = (const float*)d_in[13];
  const float* convb = (const float*)d_in[14];
  const float* Wih   = (const float*)d_in[15];
  const float* Whh   = (const float*)d_in[16];
  const float* b_ih  = (const float*)d_in[17];
  const float* b_hh  = (const float*)d_in[18];
  const float* W_out = (const float*)d_in[19];
  const float* b_out = (const float*)d_in[20];

  float* wsf = (float*)d_ws;                                   // [0..127] lossN, [128..255] M_t
  unsigned short* wbf = (unsigned short*)((char*)d_ws + 1024); // packed bf16 weights (~960 KB)

  float* out = (float*)d_out;
  size_t btd = (size_t)BQ*TT*DD;
  float* out_ximp = out;
  float* out_y    = out + btd;
  float* out_ys   = out_y + BQ;
  float* out_loss = out_ys + BQ;
  float* out_xu   = out_loss + 1;
  float* out_xrs  = out_xu + btd;

  pack_weights<<<TW_TOTAL/4, 256, 0, stream>>>(Wdec, Whist, Wv, Wr, Wih, Whh, wbf);
  msum_kernel<<<TT, 256, 0, stream>>>(m, wsf);
  scan_kernel<<<BQ/BB, NTH, 0, stream>>>(x, xhat, m, dly, b_dec, b_hist, bvv, brr,
      convw, convb, b_ih, b_hh, W_out, b_out, wbf, wsf,
      out_ximp, out_y, out_ys, out_xu, out_xrs);
  loss_final<<<1, TT, 0, stream>>>(wsf, out_loss);
}

// Round 3
// 4336.205 us; speedup vs baseline: 1.0490x; 1.0490x over previous
//
#include <hip/hip_runtime.h>
#include <math.h>

#define BQ 1024
#define TT 128
#define DD 128
#define HH 256
#define BB 16
#define NW 16
#define NTH (NW*64)
#define NBLK (BQ/BB)   // 64

typedef float f32x2 __attribute__((ext_vector_type(2)));
typedef float f32x4 __attribute__((ext_vector_type(4)));
typedef __bf16 bf16x8 __attribute__((ext_vector_type(8)));
typedef unsigned short u16x2 __attribute__((ext_vector_type(2)));
typedef unsigned short u16x8 __attribute__((ext_vector_type(8)));

// packed-weight tiles: tile = one MFMA B-fragment set = 64 lanes x 16 B = 1024 B
// B_hw[k = kb*32 + (lane>>4)*8 + e][n = nt*16 + (lane&15)] = W[n][k]
#define TW_DEC   0      // W_decay  N=256 K=128 : 64 tiles
#define TW_HIST  64     // W_hist   N=128 K=256 : 64
#define TW_WV    128    // Wv*off   N=128 K=128 : 32
#define TW_WR    160    // Wr*off   N=128 K=128 : 32
#define TW_WIH   192    // W_ih     N=768 K=256 : 384
#define TW_WHH   576    // W_hh     N=768 K=256 : 384
#define TW_TOTAL 960

// LDS byte offsets
#define L_RING 0         // 16 waves x 8 slots x 1 KB = 131072
#define L_H    131072    // h' [16][256] bf16 swz, 8192
#define L_D    139264    // d  [16][128] bf16 swz, 4096 (aliased by x_r after P0)
#define L_XR   L_D
#define L_XB   143360    // xbar       4096 (aliased by x_imp after P1)
#define L_XI   L_XB
#define L_M    147456    // m          4096
#define L_X    151552    // x bf16     4096
#define L_XU   155648    // xu bf16 [16][128] linear, 4096
#define L_RED  159744    // 8 f32
#define L_TOT  159808

__device__ __forceinline__ unsigned short f2bf(float f){
  union { float f; unsigned u; } v; v.f = f;
  unsigned r = v.u + 0x7FFFu + ((v.u >> 16) & 1u);
  return (unsigned short)(r >> 16);
}
__device__ __forceinline__ float bf2f(unsigned short u){
  union { unsigned u; float f; } v; v.u = ((unsigned)u) << 16; return v.f;
}
__device__ __forceinline__ float sigm(float v){ return 1.f/(1.f + __expf(-v)); }
__device__ __forceinline__ f32x4 mfma16(bf16x8 a, bf16x8 b, f32x4 c){
  return __builtin_amdgcn_mfma_f32_16x16x32_bf16(a, b, c, 0, 0, 0);
}
__device__ __forceinline__ void gl_lds(const unsigned short* g, char* l){
  __builtin_amdgcn_global_load_lds(
      (const __attribute__((address_space(1))) unsigned int*)g,
      (__attribute__((address_space(3))) unsigned int*)l, 16, 0, 0);
}

// tile id formulas (w, w4=w*4, w8=w*8 in scope)
#define T_DEC(k)  (TW_DEC + w4 + (k))
#define T_WHH(j)  (TW_WHH + (((j)>>3)*16 + w)*8 + ((j)&7))
#define T_HIST(j) (TW_HIST + w8 + (j))
#define T_WV(k)   (TW_WV + (w-8)*4 + (k))
#define T_WR(k)   (TW_WR + w4 + (k))
#define T_WIH(j)  (TW_WIH + (((j)>>3)*16 + w)*8 + ((j)&7))

// ring access (ring, lane8, lane16 in scope). sp = chunk parity (0/1)
#define ISSUE4(sp, T0,T1,T2,T3) do{ \
  char* rb_ = ring + (sp)*4096; \
  gl_lds(wbf + (size_t)(T0)*512 + lane8, rb_); \
  gl_lds(wbf + (size_t)(T1)*512 + lane8, rb_+1024); \
  gl_lds(wbf + (size_t)(T2)*512 + lane8, rb_+2048); \
  gl_lds(wbf + (size_t)(T3)*512 + lane8, rb_+3072); }while(0)
#define RFR(sp,k) (*(const bf16x8*)(ring + (sp)*4096 + (k)*1024 + lane16))

// pipelined chunk body: wait chunk, read frags, fence, issue chunk+2, 4x MFMA
#define BODYW(n, sp, A0,A1,A2,A3, ACC, T0,T1,T2,T3) do{ \
  asm volatile("s_waitcnt vmcnt(" #n ")" ::: "memory"); \
  bf16x8 q0_=RFR(sp,0), q1_=RFR(sp,1), q2_=RFR(sp,2), q3_=RFR(sp,3); \
  asm volatile("s_waitcnt lgkmcnt(0)" ::: "memory"); \
  ISSUE4(sp, T0,T1,T2,T3); \
  ACC = mfma16(A0,q0_,ACC); ACC = mfma16(A1,q1_,ACC); \
  ACC = mfma16(A2,q2_,ACC); ACC = mfma16(A3,q3_,ACC); \
}while(0)

// activation frag/scalar access (swizzled bf16 rows, 256 B stride)
#define ARD(base, kb) (*(const bf16x8*)(lds + (base) + lr*256 + (((kb)*64 + lg*16) ^ ((lr&7)<<4))))
#define HRD(kb)       (*(const bf16x8*)(lds + L_H   + lr*512 + (((kb)*64 + lg*16) ^ ((lr&7)<<4))))
#define SRD(base, row, col) bf2f(*(const unsigned short*)(lds + (base) + (row)*256 + ((((col)*2)) ^ (((row)&7)<<4))))
#define SWR(base, row, col, val) *(unsigned short*)(lds + (base) + (row)*256 + ((((col)*2)) ^ (((row)&7)<<4))) = f2bf(val)
#define HWR(row, col, val) *(unsigned short*)(lds + L_H + (row)*512 + ((((col)*2)) ^ (((row)&7)<<4))) = f2bf(val)

// ---------------- pack weights ----------------
__global__ void pack_weights(const float* Wdec, const float* Whist, const float* Wv,
                             const float* Wr, const float* Wih, const float* Whh,
                             unsigned short* wbf){
  int gt = blockIdx.x * 4 + (threadIdx.x >> 6);
  int lane = threadIdx.x & 63;
  if (gt >= TW_TOTAL) return;
  const float* src; int K, tl; int dm = 0;
  if (gt < TW_HIST)      { src = Wdec;  K = DD;  tl = gt; }
  else if (gt < TW_WV)   { src = Whist; K = HH;  tl = gt - TW_HIST; }
  else if (gt < TW_WR)   { src = Wv;    K = DD;  tl = gt - TW_WV;  dm = 1; }
  else if (gt < TW_WIH)  { src = Wr;    K = DD;  tl = gt - TW_WR;  dm = 1; }
  else if (gt < TW_WHH)  { src = Wih;   K = 256; tl = gt - TW_WIH; }
  else                   { src = Whh;   K = 256; tl = gt - TW_WHH; }
  int nkb = K >> 5;
  int nt = tl / nkb, kb = tl - nt*nkb;
  int n  = nt*16 + (lane & 15);
  int k0 = kb*32 + (lane >> 4)*8;
  u16x8 pk;
  #pragma unroll
  for (int e = 0; e < 8; ++e){
    int k = k0 + e;
    float wv = src[(size_t)n*K + k];
    if (dm && n == k) wv = 0.f;
    pk[e] = f2bf(wv);
  }
  *(u16x8*)(wbf + (size_t)gt*512 + lane*8) = pk;
}

// ---------------- per-step mask sums ----------------
__global__ void msum_kernel(const float* m, float* wsf){
  int t = blockIdx.x;
  float s = 0.f;
  for (int i = threadIdx.x; i < BQ*DD; i += 256){
    int b = i >> 7, d0 = i & 127;
    s += m[((size_t)b*TT + t)*DD + d0];
  }
  #pragma unroll
  for (int off = 32; off >= 1; off >>= 1) s += __shfl_down(s, off);
  __shared__ float ps[4];
  if ((threadIdx.x & 63) == 0) ps[threadIdx.x >> 6] = s;
  __syncthreads();
  if (threadIdx.x == 0) wsf[8192 + t] = ps[0] + ps[1] + ps[2] + ps[3];
}

// ---------------- final loss reduction ----------------
__global__ void loss_final(const float* wsf, float* out_loss){
  __shared__ float ps[TT];
  int t = threadIdx.x;
  float s = 0.f;
  #pragma unroll 4
  for (int b = 0; b < NBLK; ++b) s += wsf[t*NBLK + b];
  ps[t] = s / (wsf[8192 + t] + 1e-5f);
  __syncthreads();
  if (t == 0){ float a = 0.f; for (int i = 0; i < TT; ++i) a += ps[i]; *out_loss = a; }
}

// ---------------- the recurrent scan ----------------
__global__ __launch_bounds__(NTH, 4) void scan_kernel(
    const float* __restrict__ x, const float* __restrict__ xhat,
    const float* __restrict__ m, const float* __restrict__ dly,
    const float* __restrict__ b_dec, const float* __restrict__ b_hist,
    const float* __restrict__ bv, const float* __restrict__ br,
    const float* __restrict__ conv_w, const float* __restrict__ conv_b,
    const float* __restrict__ b_ih, const float* __restrict__ b_hh,
    const float* __restrict__ W_out, const float* __restrict__ b_out,
    const unsigned short* __restrict__ wbf, float* __restrict__ lossP,
    float* __restrict__ out_ximp, float* __restrict__ out_y,
    float* __restrict__ out_ys, float* __restrict__ out_xu,
    float* __restrict__ out_xrs)
{
  extern __shared__ __align__(16) char lds[];
  const int tid  = threadIdx.x;
  const int w    = tid >> 6;
  const int lane = tid & 63;
  const int lr   = lane & 15;
  const int lg   = lane >> 4;
  const int b0   = blockIdx.x * BB;
  const int w4 = w*4, w8 = w*8;
  const int lane8 = lane*8, lane16 = lane*16;
  const int colH = w*16 + lr;
  const int colD  = (w < 8) ? (w*16 + lr) : 0;
  const int colD2 = (w >= 8) ? ((w-8)*16 + lr) : 0;
  char* ring = lds + L_RING + w*8192;
  float* red = (float*)(lds + L_RED);

  const float bdec_v  = b_dec[colH];
  const float bhist_v = (w < 8) ? b_hist[colD] : 0.f;
  const float br_v    = (w < 8) ? br[colD] : 0.f;
  const float bv_v    = (w >= 8) ? bv[colD2] : 0.f;
  const float bihv0 = b_ih[colH],       bhhv0 = b_hh[colH];
  const float bihv1 = b_ih[256 + colH], bhhv1 = b_hh[256 + colH];
  const float bihv2 = b_ih[512 + colH], bhhv2 = b_hh[512 + colH];
  const float cw0 = conv_w[0], cw1 = conv_w[1], cbv = conv_b[0];
  const f32x4 z4 = {0.f, 0.f, 0.f, 0.f};

  float hst[4] = {0.f, 0.f, 0.f, 0.f};

  // staging mapping: thread stages 2 floats of row w (srow == w), cols lane*2..+1
  const int sc2 = lane*2;
  const int sboff = (lane*4) ^ ((w & 7) << 4);

  f32x2 xv, hv, mv, dv;
  // ---- prologue: inputs for t=0, chunks 0 and 1 ----
  {
    size_t g0 = ((size_t)(b0 + w)*TT + 0)*DD + sc2;
    xv = __builtin_nontemporal_load((const f32x2*)(x    + g0));
    hv = __builtin_nontemporal_load((const f32x2*)(xhat + g0));
    mv = __builtin_nontemporal_load((const f32x2*)(m    + g0));
    dv = __builtin_nontemporal_load((const f32x2*)(dly  + g0));
  }
  ISSUE4(0, T_DEC(0), T_DEC(1), T_DEC(2), T_DEC(3));
  ISSUE4(1, T_WHH(0), T_WHH(1), T_WHH(2), T_WHH(3));

  #pragma unroll 1
  for (int t = 0; t < TT; ++t){
    // ---------- staging ----------
    asm volatile("s_waitcnt vmcnt(8)" ::: "memory");
    {
      u16x2 pxb, pm, pd, px;
      #pragma unroll
      for (int e = 0; e < 2; ++e){
        pxb[e] = f2bf(mv[e]*xv[e] + (1.f - mv[e])*hv[e]);
        pm[e]  = f2bf(mv[e]);
        pd[e]  = f2bf(dv[e]);
        px[e]  = f2bf(xv[e]);
      }
      *(u16x2*)(lds + L_XB + w*256 + sboff) = pxb;
      *(u16x2*)(lds + L_M  + w*256 + sboff) = pm;
      *(u16x2*)(lds + L_D  + w*256 + sboff) = pd;
      *(u16x2*)(lds + L_X  + w*256 + sboff) = px;
    }
    __syncthreads();   // B1

    // ---------- P0: chunk0 = DEC -> gamma; h' ----------
    f32x4 ga = z4;
    {
      bf16x8 a0=ARD(L_D,0), a1=ARD(L_D,1), a2=ARD(L_D,2), a3=ARD(L_D,3);
      BODYW(4, 0, a0,a1,a2,a3, ga, T_WHH(4),T_WHH(5),T_WHH(6),T_WHH(7));
    }
    #pragma unroll
    for (int r = 0; r < 4; ++r){
      hst[r] *= __expf(-fmaxf(ga[r] + bdec_v, 0.f));
      int row = lg*4 + r;
      HWR(row, colH, hst[r]);
    }
    __syncthreads();   // B2

    // ---------- P1: WHH (all), HIST (w<8) | WV (w>=8) ----------
    bf16x8 hf0=HRD(0),hf1=HRD(1),hf2=HRD(2),hf3=HRD(3),
           hf4=HRD(4),hf5=HRD(5),hf6=HRD(6),hf7=HRD(7);
    f32x4 gh0=z4, gh1=z4, gh2=z4;
    BODYW(4, 1, hf0,hf1,hf2,hf3, gh0, T_WHH(8), T_WHH(9), T_WHH(10),T_WHH(11));
    BODYW(4, 0, hf4,hf5,hf6,hf7, gh0, T_WHH(12),T_WHH(13),T_WHH(14),T_WHH(15));
    BODYW(4, 1, hf0,hf1,hf2,hf3, gh1, T_WHH(16),T_WHH(17),T_WHH(18),T_WHH(19));
    BODYW(4, 0, hf4,hf5,hf6,hf7, gh1, T_WHH(20),T_WHH(21),T_WHH(22),T_WHH(23));
    if (w < 8){
      BODYW(4, 1, hf0,hf1,hf2,hf3, gh2, T_HIST(0),T_HIST(1),T_HIST(2),T_HIST(3));
      BODYW(4, 0, hf4,hf5,hf6,hf7, gh2, T_HIST(4),T_HIST(5),T_HIST(6),T_HIST(7));
      f32x4 xh = z4;
      BODYW(4, 1, hf0,hf1,hf2,hf3, xh, T_WR(0),T_WR(1),T_WR(2),T_WR(3));       // c7: HIST 0-3
      BODYW(4, 0, hf4,hf5,hf6,hf7, xh, T_WIH(0),T_WIH(1),T_WIH(2),T_WIH(3));   // c8: HIST 4-7
      #pragma unroll
      for (int r = 0; r < 4; ++r){
        int row = lg*4 + r;
        float mvv = SRD(L_M, row, colD);
        float xvv = SRD(L_X, row, colD);
        float xrin = mvv*xvv + (1.f - mvv)*(xh[r] + bhist_v);
        SWR(L_XR, row, colD, xrin);
      }
    } else {
      BODYW(4, 1, hf0,hf1,hf2,hf3, gh2, T_WV(0),T_WV(1),T_WV(2),T_WV(3));
      BODYW(4, 0, hf4,hf5,hf6,hf7, gh2, T_WIH(0),T_WIH(1),T_WIH(2),T_WIH(3));
      f32x4 xu4 = z4;
      {
        bf16x8 xb0=ARD(L_XB,0), xb1=ARD(L_XB,1), xb2=ARD(L_XB,2), xb3=ARD(L_XB,3);
        BODYW(4, 1, xb0,xb1,xb2,xb3, xu4, T_WIH(4),T_WIH(5),T_WIH(6),T_WIH(7)); // c7: WV
      }
      #pragma unroll
      for (int r = 0; r < 4; ++r){
        int row = lg*4 + r;
        float xuv = xu4[r] + bv_v;
        *(unsigned short*)(lds + L_XU + row*256 + colD2*2) = f2bf(xuv);
        __builtin_nontemporal_store(xuv, out_xu + ((size_t)(b0+row)*TT + t)*DD + colD2);
      }
    }
    __syncthreads();   // B3

    // ---------- P2 (w<8): WR -> xr; outputs; loss ----------
    if (w < 8){
      f32x4 xrac = z4;
      {
        bf16x8 r0=ARD(L_XR,0), r1=ARD(L_XR,1), r2=ARD(L_XR,2), r3=ARD(L_XR,3);
        BODYW(4, 1, r0,r1,r2,r3, xrac, T_WIH(4),T_WIH(5),T_WIH(6),T_WIH(7));   // c9: WR
      }
      float lpart = 0.f;
      #pragma unroll
      for (int r = 0; r < 4; ++r){
        int row = lg*4 + r;
        size_t go = ((size_t)(b0+row)*TT + t)*DD + colD;
        float xrv = xrac[r] + br_v;
        float xuv = bf2f(*(const unsigned short*)(lds + L_XU + row*256 + colD*2));
        float mvv = SRD(L_M, row, colD);
        float xvv = SRD(L_X, row, colD);
        __builtin_nontemporal_store(xrv, out_xrs + go);
        float xc = cw0*xuv + cw1*xrv + cbv;
        lpart += fabsf(xvv - xc)*mvv;
        float xi = mvv*xvv + (1.f - mvv)*xc;
        __builtin_nontemporal_store(xi, out_ximp + go);
        SWR(L_XI, row, colD, xi);
      }
      #pragma unroll
      for (int off = 32; off >= 1; off >>= 1) lpart += __shfl_down(lpart, off);
      if (lane == 0) red[w] = lpart;
    }
    __syncthreads();   // B4

    if (tid == 0){
      float s = 0.f;
      #pragma unroll
      for (int i = 0; i < 8; ++i) s += red[i];
      lossP[t*NBLK + blockIdx.x] = s;
    }

    // ---------- P3: WIH -> gi; gates; h update ----------
    {
      bf16x8 gf0=ARD(L_XI,0), gf1=ARD(L_XI,1), gf2=ARD(L_XI,2), gf3=ARD(L_XI,3);
      bf16x8 gf4=ARD(L_M,0),  gf5=ARD(L_M,1),  gf6=ARD(L_M,2),  gf7=ARD(L_M,3);
      f32x4 gi0=z4, gi1=z4, gi2=z4;
      if (w < 8){
        BODYW(12, 0, gf0,gf1,gf2,gf3, gi0, T_WIH(8), T_WIH(9), T_WIH(10),T_WIH(11));
        BODYW(12, 1, gf4,gf5,gf6,gf7, gi0, T_WIH(12),T_WIH(13),T_WIH(14),T_WIH(15));
      } else {
        BODYW(8, 0, gf0,gf1,gf2,gf3, gi0, T_WIH(8), T_WIH(9), T_WIH(10),T_WIH(11));
        BODYW(8, 1, gf4,gf5,gf6,gf7, gi0, T_WIH(12),T_WIH(13),T_WIH(14),T_WIH(15));
      }
      BODYW(4, 0, gf0,gf1,gf2,gf3, gi1, T_WIH(16),T_WIH(17),T_WIH(18),T_WIH(19));
      BODYW(4, 1, gf4,gf5,gf6,gf7, gi1, T_WIH(20),T_WIH(21),T_WIH(22),T_WIH(23));
      // input loads for next step (issued here, consumed at next staging)
      {
        int tn = (t < TT-1) ? t+1 : t;
        size_t g2 = ((size_t)(b0 + w)*TT + tn)*DD + sc2;
        xv = __builtin_nontemporal_load((const f32x2*)(x    + g2));
        hv = __builtin_nontemporal_load((const f32x2*)(xhat + g2));
        mv = __builtin_nontemporal_load((const f32x2*)(m    + g2));
        dv = __builtin_nontemporal_load((const f32x2*)(dly  + g2));
      }
      BODYW(4, 0, gf0,gf1,gf2,gf3, gi2, T_DEC(0),T_DEC(1),T_DEC(2),T_DEC(3));  // next-step c0
      BODYW(4, 1, gf4,gf5,gf6,gf7, gi2, T_WHH(0),T_WHH(1),T_WHH(2),T_WHH(3));  // next-step c1
      #pragma unroll
      for (int r = 0; r < 4; ++r){
        float rr = sigm(gi0[r] + bihv0 + gh0[r] + bhhv0);
        float zz = sigm(gi1[r] + bihv1 + gh1[r] + bhhv1);
        float nn = tanhf(gi2[r] + bihv2 + rr*(gh2[r] + bhhv2));
        hst[r] = (1.f - zz)*nn + zz*hst[r];
      }
    }
    __syncthreads();   // B5
  }

  // ---- epilogue: y_out = h_fin @ W_out^T + b_out ----
  asm volatile("s_waitcnt vmcnt(0)" ::: "memory");
  __syncthreads();
  float* hfin = (float*)(lds);          // reuse ring area: [16][256] f32
  #pragma unroll
  for (int r = 0; r < 4; ++r)
    hfin[(lg*4 + r)*HH + colH] = hst[r];
  __syncthreads();
  float* psum = (float*)(lds + 16384);  // 256 f32
  if (tid < 256){
    int row = tid >> 4, seg = tid & 15;
    float p = 0.f;
    #pragma unroll
    for (int c = 0; c < 16; ++c) p += hfin[row*HH + seg*16 + c]*W_out[seg*16 + c];
    psum[tid] = p;
  }
  __syncthreads();
  if (tid < 16){
    float yv = b_out[0];
    #pragma unroll
    for (int i = 0; i < 16; ++i) yv += psum[tid*16 + i];
    out_y[b0 + tid] = yv;
    out_ys[b0 + tid] = sigm(yv);
  }
}

extern "C" void kernel_launch(void* const* d_in, const int* in_sizes, int n_in,
                              void* d_out, int out_size, void* d_ws, size_t ws_size,
                              hipStream_t stream){
  const float* x     = (const float*)d_in[0];
  const float* xhat  = (const float*)d_in[1];
  const float* m     = (const float*)d_in[3];
  const float* dly   = (const float*)d_in[4];
  const float* Wdec  = (const float*)d_in[5];
  const float* b_dec = (const float*)d_in[6];
  const float* Whist = (const float*)d_in[7];
  const float* b_hist= (const float*)d_in[8];
  const float* Wv    = (const float*)d_in[9];
  const float* bvv   = (const float*)d_in[10];
  const float* Wr    = (const float*)d_in[11];
  const float* brr   = (const float*)d_in[12];
  const float* convw = (const float*)d_in[13];
  const float* convb = (const float*)d_in[14];
  const float* Wih   = (const float*)d_in[15];
  const float* Whh   = (const float*)d_in[16];
  const float* b_ih  = (const float*)d_in[17];
  const float* b_hh  = (const float*)d_in[18];
  const float* W_out = (const float*)d_in[19];
  const float* b_out = (const float*)d_in[20];

  float* wsf = (float*)d_ws;   // [0..8191] lossPart[t][blk], [8192..8319] M_t
  unsigned short* wbf = (unsigned short*)((char*)d_ws + 33792);

  float* out = (float*)d_out;
  size_t btd = (size_t)BQ*TT*DD;
  float* out_ximp = out;
  float* out_y    = out + btd;
  float* out_ys   = out_y + BQ;
  float* out_loss = out_ys + BQ;
  float* out_xu   = out_loss + 1;
  float* out_xrs  = out_xu + btd;

  (void)hipFuncSetAttribute((const void*)scan_kernel,
                            hipFuncAttributeMaxDynamicSharedMemorySize, L_TOT);

  pack_weights<<<TW_TOTAL/4, 256, 0, stream>>>(Wdec, Whist, Wv, Wr, Wih, Whh, wbf);
  msum_kernel<<<TT, 256, 0, stream>>>(m, wsf);
  scan_kernel<<<NBLK, NTH, L_TOT, stream>>>(x, xhat, m, dly, b_dec, b_hist, bvv, brr,
      convw, convb, b_ih, b_hh, W_out, b_out, wbf, wsf,
      out_ximp, out_y, out_ys, out_xu, out_xrs);
  loss_final<<<1, TT, 0, stream>>>(wsf, out_loss);
}

// Round 4
// 1282.991 us; speedup vs baseline: 3.5455x; 3.3798x over previous
//
#include <hip/hip_runtime.h>
#include <math.h>

#define BQ 1024
#define TT 128
#define DD 128
#define HH 256
#define NW 8
#define NTH 512
#define NBLK 64

typedef float f32x4 __attribute__((ext_vector_type(4)));
typedef __bf16 bf16x8 __attribute__((ext_vector_type(8)));
typedef unsigned short u16x4 __attribute__((ext_vector_type(4)));
typedef unsigned short u16x8 __attribute__((ext_vector_type(8)));
typedef unsigned int u32x4 __attribute__((ext_vector_type(4)));
typedef long long i64;

// ---- ws layout (bytes) ----
#define WS_MSUMF 8192       // float index of msums (byte 32768)
#define WS_WQ8   40960      // 864 fp8 tiles * 512 B
#define WS_WB16  524288     // 96 bf16 tiles * 1024 B
#define WS_SA    1048576    // stream records: [t][blk][tid] * 48 B  (~192 MB)

// fp8 tile id bases (each tile = 64 lanes x 8 B = 512 B)
#define TQ_WHH  0     // 384: [(g*16+nt)*8+kt]  Whh[768][256]
#define TQ_WIHM 384   // 192: [(g*16+nt)*4+kt]  Wih[:,128:256]
#define TQ_WIHX 576   // 192: [(g*16+nt)*4+kt]  Wih[:,0:128]
#define TQ_HIST 768   // 64:  [nt*8+kt]         Whist[128][256]
#define TQ_WR   832   // 32:  [nt*4+kt]         Wr[128][128] diag0
#define TQ_TOT  864

// bf16 tile id bases (each tile = 64 lanes x 16 B = 1024 B)
#define TB_DEC 0      // 64: [nt*4+kt] Wdec[256][128]
#define TB_WV  64     // 32: [nt*4+kt] Wv[128][128] diag0
#define TB_TOT 96

// ---- scan LDS map (bytes) ----
#define L_WX  0        // wihx fp8 tiles 192*512 = 98304
#define L_HI  98304    // hist 64*512 = 32768
#define L_WR2 131072   // wr 32*512 = 16384
#define L_HP  147456   // h' bf16 A-frags [8 kt][64 lane][16 B] = 8192
#define L_XRF 155648   // x_r fp8 A-frags [4 kt][64][8] = 2048
#define L_XIF 157696   // x_imp fp8 frags = 2048
#define L_MF  159744   // m fp8 frags = 2048
#define L_RED 161792   // 16 f32
#define L_TOT 161856

__device__ __forceinline__ unsigned short f2bf(float f){
  union { float f; unsigned u; } v; v.f = f;
  unsigned r = v.u + 0x7FFFu + ((v.u >> 16) & 1u);
  return (unsigned short)(r >> 16);
}
__device__ __forceinline__ float bf2f(unsigned short u){
  union { unsigned u; float f; } v; v.u = ((unsigned)u) << 16; return v.f;
}
__device__ __forceinline__ float sigm(float v){ return 1.f/(1.f + __expf(-v)); }
__device__ __forceinline__ float tanhfast(float v){ return 2.f*sigm(2.f*v) - 1.f; }
__device__ __forceinline__ unsigned pk4(float a, float b, float c, float d){
  int v = __builtin_amdgcn_cvt_pk_fp8_f32(a, b, 0, false);
  v = __builtin_amdgcn_cvt_pk_fp8_f32(c, d, v, true);
  return (unsigned)v;
}
__device__ __forceinline__ unsigned pk2(unsigned short a, unsigned short b){
  return (unsigned)a | ((unsigned)b << 16);
}
__device__ __forceinline__ f32x4 mfma8(i64 a, i64 b, f32x4 c){
  return __builtin_amdgcn_mfma_f32_16x16x32_fp8_fp8(a, b, c, 0, 0, 0);
}
__device__ __forceinline__ f32x4 mfma16b(bf16x8 a, bf16x8 b, f32x4 c){
  return __builtin_amdgcn_mfma_f32_16x16x32_bf16(a, b, c, 0, 0, 0);
}

// ---------------- pack fp8 weight tiles ----------------
__global__ void pack_w8(const float* Whh, const float* Wih, const float* Whist,
                        const float* Wr, unsigned char* wq){
  int gt = blockIdx.x*4 + (threadIdx.x>>6);
  int lane = threadIdx.x & 63;
  if (gt >= TQ_TOT) return;
  int lr = lane & 15, lg = lane >> 4;
  const float* src; int n, k0, K; int dm = 0;
  if (gt < TQ_WIHM){ int id = gt; int kt = id & 7, gnt = id >> 3;
    n = (gnt>>4)*256 + (gnt&15)*16 + lr; k0 = kt*32 + lg*8; src = Whh; K = 256; }
  else if (gt < TQ_WIHX){ int id = gt - TQ_WIHM; int kt = id & 3, gnt = id >> 2;
    n = (gnt>>4)*256 + (gnt&15)*16 + lr; k0 = 128 + kt*32 + lg*8; src = Wih; K = 256; }
  else if (gt < TQ_HIST){ int id = gt - TQ_WIHX; int kt = id & 3, gnt = id >> 2;
    n = (gnt>>4)*256 + (gnt&15)*16 + lr; k0 = kt*32 + lg*8; src = Wih; K = 256; }
  else if (gt < TQ_WR){ int id = gt - TQ_HIST; int kt = id & 7, nt = id >> 3;
    n = nt*16 + lr; k0 = kt*32 + lg*8; src = Whist; K = 256; }
  else { int id = gt - TQ_WR; int kt = id & 3, nt = id >> 2;
    n = nt*16 + lr; k0 = kt*32 + lg*8; src = Wr; K = 128; dm = 1; }
  float f[8];
  #pragma unroll
  for (int e = 0; e < 8; ++e){
    int k = k0 + e;
    float v = src[(size_t)n*K + k];
    if (dm && n == k) v = 0.f;
    f[e] = v;
  }
  unsigned lo = pk4(f[0],f[1],f[2],f[3]), hi = pk4(f[4],f[5],f[6],f[7]);
  *(unsigned*)(wq + (size_t)gt*512 + lane*8) = lo;
  *(unsigned*)(wq + (size_t)gt*512 + lane*8 + 4) = hi;
}

// ---------------- pack bf16 tiles (prep weights) ----------------
__global__ void pack_w16(const float* Wdec, const float* Wv, unsigned short* wb){
  int gt = blockIdx.x*4 + (threadIdx.x>>6);
  int lane = threadIdx.x & 63;
  if (gt >= TB_TOT) return;
  int lr = lane & 15, lg = lane >> 4;
  const float* src; int n; int dm = 0;
  int kt;
  if (gt < TB_WV){ kt = gt & 3; n = (gt>>2)*16 + lr; src = Wdec; }
  else { int id = gt - TB_WV; kt = id & 3; n = (id>>2)*16 + lr; src = Wv; dm = 1; }
  int k0 = kt*32 + lg*8;
  u16x8 pkv;
  #pragma unroll
  for (int e = 0; e < 8; ++e){
    int k = k0 + e;
    float v = src[(size_t)n*128 + k];
    if (dm && n == k) v = 0.f;
    pkv[e] = f2bf(v);
  }
  *(u16x8*)(wb + (size_t)gt*512 + lane*8) = pkv;
}

// ---------------- per-step mask sums ----------------
__global__ void msum_kernel(const float* m, float* wsf){
  int t = blockIdx.x;
  float s = 0.f;
  for (int i = threadIdx.x; i < BQ*DD; i += 256){
    int b = i >> 7, d0 = i & 127;
    s += m[((size_t)b*TT + t)*DD + d0];
  }
  #pragma unroll
  for (int off = 32; off >= 1; off >>= 1) s += __shfl_down(s, off);
  __shared__ float ps[4];
  if ((threadIdx.x & 63) == 0) ps[threadIdx.x >> 6] = s;
  __syncthreads();
  if (threadIdx.x == 0) wsf[WS_MSUMF + t] = ps[0] + ps[1] + ps[2] + ps[3];
}

// ---------------- final loss reduction ----------------
__global__ void loss_final(const float* wsf, float* out_loss){
  __shared__ float ps[TT];
  int t = threadIdx.x;
  float s = 0.f;
  #pragma unroll 4
  for (int b = 0; b < NBLK; ++b) s += wsf[t*NBLK + b];
  ps[t] = s / (wsf[WS_MSUMF + t] + 1e-5f);
  __syncthreads();
  if (t == 0){ float a = 0.f; for (int i = 0; i < TT; ++i) a += ps[i]; *out_loss = a; }
}

// ---------------- prep: gamma/xu + stream relayout ----------------
__global__ __launch_bounds__(NTH, 2) void prep_kernel(
    const float* __restrict__ x, const float* __restrict__ xhat,
    const float* __restrict__ m, const float* __restrict__ dly,
    const float* __restrict__ b_dec, const float* __restrict__ bv,
    const unsigned short* __restrict__ wb, unsigned* __restrict__ sa,
    float* __restrict__ out_xu)
{
  __shared__ __align__(16) char sm[16384];  // d-frag 4K | xb-frag 4K | x 4K | m 4K
  const int tid = threadIdx.x, w = tid>>6, lane = tid&63, lr = lane&15, lg = lane>>4;
  const int btile = blockIdx.x >> 3, tch = blockIdx.x & 7, b0 = btile*16;
  const int colD = w*16 + lr, colH0 = w*32 + lr;
  bf16x8 decR[2][4], wvR[4];
  #pragma unroll
  for (int s = 0; s < 2; ++s)
    #pragma unroll
    for (int kt = 0; kt < 4; ++kt)
      decR[s][kt] = *(const bf16x8*)(wb + (size_t)(TB_DEC + (w*2+s)*4 + kt)*512 + lane*8);
  #pragma unroll
  for (int kt = 0; kt < 4; ++kt)
    wvR[kt] = *(const bf16x8*)(wb + (size_t)(TB_WV + w*4 + kt)*512 + lane*8);
  const float bd0 = b_dec[colH0], bd1 = b_dec[colH0+16], bvv = bv[colD];
  const int srow = tid >> 5, c4 = (tid & 31)*4;
  const int kt_ = c4 >> 5, dl_ = ((c4 & 31) >> 3)*16 + srow, e0_ = c4 & 7;

  for (int tt = 0; tt < 16; ++tt){
    int tg = tch*16 + tt;
    size_t gofs = ((size_t)(b0 + srow)*TT + tg)*DD + c4;
    f32x4 xv = __builtin_nontemporal_load((const f32x4*)(x + gofs));
    f32x4 hv = __builtin_nontemporal_load((const f32x4*)(xhat + gofs));
    f32x4 mv = __builtin_nontemporal_load((const f32x4*)(m + gofs));
    f32x4 dv = __builtin_nontemporal_load((const f32x4*)(dly + gofs));
    u16x4 pd, pxb, px, pm;
    #pragma unroll
    for (int e = 0; e < 4; ++e){
      pd[e]  = f2bf(dv[e]);
      pxb[e] = f2bf(mv[e]*xv[e] + (1.f - mv[e])*hv[e]);
      px[e]  = f2bf(xv[e]);
      pm[e]  = f2bf(mv[e]);
    }
    *(u16x4*)(sm + 0     + kt_*1024 + dl_*16 + e0_*2) = pd;
    *(u16x4*)(sm + 4096  + kt_*1024 + dl_*16 + e0_*2) = pxb;
    *(u16x4*)(sm + 8192  + srow*256 + c4*2) = px;
    *(u16x4*)(sm + 12288 + srow*256 + c4*2) = pm;
    __syncthreads();

    f32x4 ga0 = {0.f,0.f,0.f,0.f}, ga1 = {0.f,0.f,0.f,0.f}, xu4 = {0.f,0.f,0.f,0.f};
    #pragma unroll
    for (int kt = 0; kt < 4; ++kt){
      bf16x8 df  = *(const bf16x8*)(sm + 0    + kt*1024 + lane*16);
      bf16x8 xbf = *(const bf16x8*)(sm + 4096 + kt*1024 + lane*16);
      ga0 = mfma16b(df, decR[0][kt], ga0);
      ga1 = mfma16b(df, decR[1][kt], ga1);
      xu4 = mfma16b(xbf, wvR[kt], xu4);
    }
    unsigned short g8[8], xm8[8];
    float xuo[4];
    #pragma unroll
    for (int r = 0; r < 4; ++r){
      g8[r]   = f2bf(__expf(-fmaxf(ga0[r] + bd0, 0.f)));
      g8[4+r] = f2bf(__expf(-fmaxf(ga1[r] + bd1, 0.f)));
      int row = lg*4 + r;
      xm8[r]   = *(const unsigned short*)(sm + 8192  + row*256 + colD*2);
      xm8[4+r] = *(const unsigned short*)(sm + 12288 + row*256 + colD*2);
      xuo[r] = xu4[r] + bvv;
    }
    unsigned* rp = sa + (((size_t)tg*NBLK + btile)*512 + tid)*12;
    u32x4 r0 = {pk2(g8[0],g8[1]), pk2(g8[2],g8[3]), pk2(g8[4],g8[5]), pk2(g8[6],g8[7])};
    u32x4 r1 = {pk2(xm8[0],xm8[1]), pk2(xm8[2],xm8[3]), pk2(xm8[4],xm8[5]), pk2(xm8[6],xm8[7])};
    u32x4 r2 = {pk2(f2bf(xuo[0]),f2bf(xuo[1])), pk2(f2bf(xuo[2]),f2bf(xuo[3])), 0u, 0u};
    __builtin_nontemporal_store(r0, (u32x4*)rp);
    __builtin_nontemporal_store(r1, (u32x4*)(rp+4));
    __builtin_nontemporal_store(r2, (u32x4*)(rp+8));
    #pragma unroll
    for (int r = 0; r < 4; ++r)
      __builtin_nontemporal_store(xuo[r], out_xu + ((size_t)(b0 + lg*4 + r)*TT + tg)*DD + colD);
    __syncthreads();
  }
}

// ---------------- the weight-stationary recurrent scan ----------------
__global__ __launch_bounds__(NTH, 2) void scan_kernel(
    const unsigned char* __restrict__ wq, const unsigned* __restrict__ sa,
    const float* __restrict__ b_hist, const float* __restrict__ br,
    const float* __restrict__ b_ih, const float* __restrict__ b_hh,
    const float* __restrict__ conv_w, const float* __restrict__ conv_b,
    const float* __restrict__ W_out, const float* __restrict__ b_out,
    float* __restrict__ lossP,
    float* __restrict__ out_ximp, float* __restrict__ out_y,
    float* __restrict__ out_ys, float* __restrict__ out_xrs)
{
  extern __shared__ __align__(16) char lds[];
  const int tid = threadIdx.x, w = tid>>6, lane = tid&63, lr = lane&15, lg = lane>>4;
  const int b0 = blockIdx.x*16;
  const int colD = w*16 + lr, colH0 = w*32 + lr;

  // resident weight registers (fp8): Whh full + Wih_m slice
  i64 whhR[3][2][8], wihmR[3][2][4];
  #pragma unroll
  for (int g = 0; g < 3; ++g)
    #pragma unroll
    for (int s = 0; s < 2; ++s){
      #pragma unroll
      for (int kt = 0; kt < 8; ++kt)
        whhR[g][s][kt] = *(const i64*)(wq + (size_t)(TQ_WHH + ((g*16 + w*2+s)*8 + kt))*512 + lane*8);
      #pragma unroll
      for (int kt = 0; kt < 4; ++kt)
        wihmR[g][s][kt] = *(const i64*)(wq + (size_t)(TQ_WIHM + ((g*16 + w*2+s)*4 + kt))*512 + lane*8);
    }
  // LDS-resident weights: wihx + hist + wr (tiles 576..863, contiguous)
  for (int i = tid; i < 147456/16; i += NTH)
    *(u32x4*)(lds + (size_t)i*16) = *(const u32x4*)(wq + (size_t)576*512 + (size_t)i*16);

  const float bhist_v = b_hist[colD], br_v = br[colD];
  float brz[2][2], bihn[2], bhhn[2];
  #pragma unroll
  for (int s = 0; s < 2; ++s){
    int cH = colH0 + s*16;
    brz[0][s] = b_ih[cH] + b_hh[cH];
    brz[1][s] = b_ih[256+cH] + b_hh[256+cH];
    bihn[s] = b_ih[512+cH]; bhhn[s] = b_hh[512+cH];
  }
  const float cw0 = conv_w[0], cw1 = conv_w[1], cb = conv_b[0];

  const int hp0 = L_HP + w*1024 + ((lr>>3)*16 + lg*4)*16 + (lr&7)*2;   // + s*512 + r*16
  const int f80 = (w>>1)*512 + ((w&1)*2 + (lr>>3))*128 + lg*32 + (lr&7); // + r*8
  float* red = (float*)(lds + L_RED);

  float hs[2][4] = {{0.f,0.f,0.f,0.f},{0.f,0.f,0.f,0.f}};

  const unsigned* recp = sa + ((size_t)blockIdx.x*512 + tid)*12;
  u32x4 pfA = __builtin_nontemporal_load((const u32x4*)recp);
  u32x4 pfB = __builtin_nontemporal_load((const u32x4*)(recp+4));
  u32x4 pfC = __builtin_nontemporal_load((const u32x4*)(recp+8));

  #pragma unroll 1
  for (int t = 0; t < TT; ++t){
    // ---------- PH0: h *= gamma; stage h'/m frags ----------
    asm volatile("s_waitcnt vmcnt(0)" ::: "memory");
    __builtin_amdgcn_sched_barrier(0);
    #pragma unroll
    for (int s = 0; s < 2; ++s)
      #pragma unroll
      for (int r = 0; r < 4; ++r){
        unsigned word = pfA[(s*4+r)>>1];
        float g = bf2f((unsigned short)(((s*4+r)&1) ? (word>>16) : word));
        hs[s][r] *= g;
        *(unsigned short*)(lds + hp0 + s*512 + r*16) = f2bf(hs[s][r]);
      }
    #pragma unroll
    for (int r = 0; r < 4; ++r){
      unsigned word = pfB[2 + (r>>1)];
      unsigned short mu = (unsigned short)((r&1) ? (word>>16) : word);
      *(unsigned char*)(lds + L_MF + f80 + r*8) = mu ? 0x38 : 0x00;
    }
    __syncthreads();  // B1

    // ---------- PH1: gh + gim + xh ----------
    i64 ha[8];
    #pragma unroll
    for (int kt = 0; kt < 8; ++kt){
      u16x8 hv = *(const u16x8*)(lds + L_HP + kt*1024 + lane*16);
      unsigned lo = pk4(bf2f(hv[0]),bf2f(hv[1]),bf2f(hv[2]),bf2f(hv[3]));
      unsigned hi = pk4(bf2f(hv[4]),bf2f(hv[5]),bf2f(hv[6]),bf2f(hv[7]));
      ha[kt] = (i64)(((unsigned long long)hi << 32) | lo);
    }
    i64 ma[4];
    #pragma unroll
    for (int kt = 0; kt < 4; ++kt) ma[kt] = *(const i64*)(lds + L_MF + kt*512 + lane*8);

    f32x4 z4 = {0.f,0.f,0.f,0.f};
    f32x4 aRZ[2][2] = {{z4,z4},{z4,z4}};
    f32x4 aNh[2] = {z4,z4}, aNi[2] = {z4,z4}, xh4 = z4;
    #pragma unroll
    for (int s = 0; s < 2; ++s)
      #pragma unroll
      for (int kt = 0; kt < 8; ++kt){
        aRZ[0][s] = mfma8(ha[kt], whhR[0][s][kt], aRZ[0][s]);
        aRZ[1][s] = mfma8(ha[kt], whhR[1][s][kt], aRZ[1][s]);
        aNh[s]    = mfma8(ha[kt], whhR[2][s][kt], aNh[s]);
      }
    #pragma unroll
    for (int kt = 0; kt < 8; ++kt)
      xh4 = mfma8(ha[kt], *(const i64*)(lds + L_HI + (w*8+kt)*512 + lane*8), xh4);
    #pragma unroll
    for (int s = 0; s < 2; ++s)
      #pragma unroll
      for (int kt = 0; kt < 4; ++kt){
        aRZ[0][s] = mfma8(ma[kt], wihmR[0][s][kt], aRZ[0][s]);
        aRZ[1][s] = mfma8(ma[kt], wihmR[1][s][kt], aRZ[1][s]);
        aNi[s]    = mfma8(ma[kt], wihmR[2][s][kt], aNi[s]);
      }
    float xv_[4], mv_[4];
    #pragma unroll
    for (int r = 0; r < 4; ++r){
      unsigned wx = pfB[r>>1];
      xv_[r] = bf2f((unsigned short)((r&1) ? (wx>>16) : wx));
      unsigned wm = pfB[2 + (r>>1)];
      mv_[r] = bf2f((unsigned short)((r&1) ? (wm>>16) : wm));
    }
    {
      float x0 = mv_[0]*xv_[0] + (1.f-mv_[0])*(xh4[0] + bhist_v);
      float x1 = mv_[1]*xv_[1] + (1.f-mv_[1])*(xh4[1] + bhist_v);
      float x2 = mv_[2]*xv_[2] + (1.f-mv_[2])*(xh4[2] + bhist_v);
      float x3 = mv_[3]*xv_[3] + (1.f-mv_[3])*(xh4[3] + bhist_v);
      unsigned p = pk4(x0, x1, x2, x3);
      #pragma unroll
      for (int r = 0; r < 4; ++r)
        *(unsigned char*)(lds + L_XRF + f80 + r*8) = (unsigned char)((p >> (8*r)) & 0xff);
    }
    __syncthreads();  // B2

    // ---------- PH2: xr, outputs, loss, x_imp ----------
    f32x4 xr4 = z4;
    #pragma unroll
    for (int kt = 0; kt < 4; ++kt)
      xr4 = mfma8(*(const i64*)(lds + L_XRF + kt*512 + lane*8),
                  *(const i64*)(lds + L_WR2 + (w*4+kt)*512 + lane*8), xr4);
    float lpart = 0.f, xi_[4];
    #pragma unroll
    for (int r = 0; r < 4; ++r){
      int row = lg*4 + r;
      size_t go = ((size_t)(b0+row)*TT + t)*DD + colD;
      float xrv = xr4[r] + br_v;
      unsigned wu = pfC[r>>1];
      float xuv = bf2f((unsigned short)((r&1) ? (wu>>16) : wu));
      __builtin_nontemporal_store(xrv, out_xrs + go);
      float xc = cw0*xuv + cw1*xrv + cb;
      lpart += fabsf(xv_[r] - xc)*mv_[r];
      xi_[r] = mv_[r]*xv_[r] + (1.f - mv_[r])*xc;
      __builtin_nontemporal_store(xi_[r], out_ximp + go);
    }
    {
      unsigned q = pk4(xi_[0], xi_[1], xi_[2], xi_[3]);
      #pragma unroll
      for (int r = 0; r < 4; ++r)
        *(unsigned char*)(lds + L_XIF + f80 + r*8) = (unsigned char)((q >> (8*r)) & 0xff);
    }
    #pragma unroll
    for (int off = 32; off >= 1; off >>= 1) lpart += __shfl_down(lpart, off);
    if (lane == 0) red[(t&1)*8 + w] = lpart;
    recp += (size_t)NBLK*512*12;
    if (t < TT-1){
      pfA = __builtin_nontemporal_load((const u32x4*)recp);
      pfB = __builtin_nontemporal_load((const u32x4*)(recp+4));
      pfC = __builtin_nontemporal_load((const u32x4*)(recp+8));
    }
    __syncthreads();  // B3

    // ---------- PH3: gi_x + gates + h update ----------
    i64 xia[4];
    #pragma unroll
    for (int kt = 0; kt < 4; ++kt) xia[kt] = *(const i64*)(lds + L_XIF + kt*512 + lane*8);
    #pragma unroll
    for (int s = 0; s < 2; ++s)
      #pragma unroll
      for (int kt = 0; kt < 4; ++kt){
        aRZ[0][s] = mfma8(xia[kt], *(const i64*)(lds + L_WX + ((0*16 + w*2+s)*4 + kt)*512 + lane*8), aRZ[0][s]);
        aRZ[1][s] = mfma8(xia[kt], *(const i64*)(lds + L_WX + ((1*16 + w*2+s)*4 + kt)*512 + lane*8), aRZ[1][s]);
        aNi[s]    = mfma8(xia[kt], *(const i64*)(lds + L_WX + ((2*16 + w*2+s)*4 + kt)*512 + lane*8), aNi[s]);
      }
    if (tid == 0){
      float ssum = 0.f;
      #pragma unroll
      for (int i = 0; i < 8; ++i) ssum += red[(t&1)*8 + i];
      lossP[t*NBLK + blockIdx.x] = ssum;
    }
    #pragma unroll
    for (int s = 0; s < 2; ++s)
      #pragma unroll
      for (int r = 0; r < 4; ++r){
        float rr = sigm(aRZ[0][s][r] + brz[0][s]);
        float zz = sigm(aRZ[1][s][r] + brz[1][s]);
        float hn = aNh[s][r] + bhhn[s];
        float nn = tanhfast(aNi[s][r] + bihn[s] + rr*hn);
        hs[s][r] = (1.f - zz)*nn + zz*hs[s][r];
      }
  }

  // ---------- epilogue: y = h_fin @ W_out^T + b ----------
  __syncthreads();
  float* hfin = (float*)lds;
  #pragma unroll
  for (int s = 0; s < 2; ++s)
    #pragma unroll
    for (int r = 0; r < 4; ++r)
      hfin[(lg*4+r)*HH + colH0 + s*16] = hs[s][r];
  __syncthreads();
  float* psum = (float*)(lds + 16384);
  if (tid < 256){
    int row = tid >> 4, seg = tid & 15;
    float p = 0.f;
    #pragma unroll
    for (int c = 0; c < 16; ++c) p += hfin[row*HH + seg*16 + c]*W_out[seg*16 + c];
    psum[tid] = p;
  }
  __syncthreads();
  if (tid < 16){
    float yv = b_out[0];
    #pragma unroll
    for (int i = 0; i < 16; ++i) yv += psum[tid*16 + i];
    out_y[b0 + tid] = yv;
    out_ys[b0 + tid] = sigm(yv);
  }
}

extern "C" void kernel_launch(void* const* d_in, const int* in_sizes, int n_in,
                              void* d_out, int out_size, void* d_ws, size_t ws_size,
                              hipStream_t stream){
  const float* x     = (const float*)d_in[0];
  const float* xhat  = (const float*)d_in[1];
  const float* m     = (const float*)d_in[3];
  const float* dly   = (const float*)d_in[4];
  const float* Wdec  = (const float*)d_in[5];
  const float* b_dec = (const float*)d_in[6];
  const float* Whist = (const float*)d_in[7];
  const float* b_hist= (const float*)d_in[8];
  const float* Wv    = (const float*)d_in[9];
  const float* bvv   = (const float*)d_in[10];
  const float* Wr    = (const float*)d_in[11];
  const float* brr   = (const float*)d_in[12];
  const float* convw = (const float*)d_in[13];
  const float* convb = (const float*)d_in[14];
  const float* Wih   = (const float*)d_in[15];
  const float* Whh   = (const float*)d_in[16];
  const float* b_ih  = (const float*)d_in[17];
  const float* b_hh  = (const float*)d_in[18];
  const float* W_out = (const float*)d_in[19];
  const float* b_out = (const float*)d_in[20];

  float* wsf = (float*)d_ws;                    // [0..8191] lossP[t][blk], [8192..8319] msums
  unsigned char* wq = (unsigned char*)d_ws + WS_WQ8;
  unsigned short* wb = (unsigned short*)((char*)d_ws + WS_WB16);
  unsigned* sa = (unsigned*)((char*)d_ws + WS_SA);

  float* out = (float*)d_out;
  size_t btd = (size_t)BQ*TT*DD;
  float* out_ximp = out;
  float* out_y    = out + btd;
  float* out_ys   = out_y + BQ;
  float* out_loss = out_ys + BQ;
  float* out_xu   = out_loss + 1;
  float* out_xrs  = out_xu + btd;

  (void)hipFuncSetAttribute((const void*)scan_kernel,
                            hipFuncAttributeMaxDynamicSharedMemorySize, L_TOT);

  pack_w8<<<TQ_TOT/4, 256, 0, stream>>>(Whh, Wih, Whist, Wr, wq);
  pack_w16<<<TB_TOT/4, 256, 0, stream>>>(Wdec, Wv, wb);
  msum_kernel<<<TT, 256, 0, stream>>>(m, wsf);
  prep_kernel<<<512, NTH, 0, stream>>>(x, xhat, m, dly, b_dec, bvv, wb, sa, out_xu);
  scan_kernel<<<NBLK, NTH, L_TOT, stream>>>(wq, sa, b_hist, brr, b_ih, b_hh,
      convw, convb, W_out, b_out, wsf,
      out_ximp, out_y, out_ys, out_xrs);
  loss_final<<<1, TT, 0, stream>>>(wsf, out_loss);
}

// Round 5
// 971.427 us; speedup vs baseline: 4.6826x; 1.3207x over previous
//
#include <hip/hip_runtime.h>
#include <math.h>

#define BQ 1024
#define TT 128
#define DD 128
#define HH 256
#define NW 8
#define NTH 512
#define NBLK 64

typedef float f32x4 __attribute__((ext_vector_type(4)));
typedef __bf16 bf16x8 __attribute__((ext_vector_type(8)));
typedef unsigned short u16x4 __attribute__((ext_vector_type(4)));
typedef unsigned short u16x8 __attribute__((ext_vector_type(8)));
typedef unsigned int u32x4 __attribute__((ext_vector_type(4)));
typedef unsigned int u32x2 __attribute__((ext_vector_type(2)));
typedef long long i64;

// ---- ws layout (bytes) ----
#define WS_MSUMF 8192       // float index of msums (byte 32768)
#define WS_WQ8   40960      // 864 fp8 tiles * 512 B
#define WS_WB16  524288     // 96 bf16 tiles * 1024 B
#define WS_SA    1048576    // stream records: [t][blk][tid] * 48 B  (~192 MB)

// fp8 tile id bases (each tile = 64 lanes x 8 B = 512 B)
#define TQ_WHH  0     // 384: [(g*16+nt)*8+kt]  Whh[768][256]
#define TQ_WIHM 384   // 192: [(g*16+nt)*4+kt]  Wih[:,128:256]
#define TQ_WIHX 576   // 192: [(g*16+nt)*4+kt]  Wih[:,0:128]
#define TQ_HIST 768   // 64:  [nt*8+kt]         Whist[128][256]
#define TQ_WR   832   // 32:  [nt*4+kt]         Wr[128][128] diag0
#define TQ_TOT  864

// bf16 tile id bases (each tile = 64 lanes x 16 B = 1024 B)
#define TB_DEC 0      // 64: [nt*4+kt] Wdec[256][128]
#define TB_WV  64     // 32: [nt*4+kt] Wv[128][128] diag0
#define TB_TOT 96

// ---- scan LDS map (bytes) ----
#define L_WX  0        // wihx fp8 tiles 192*512 = 98304
#define L_HI  98304    // hist 64*512 = 32768
#define L_WR2 131072   // wr 32*512 = 16384
#define L_HF8 147456   // h' fp8 A-frags [8 kt][64 lane][8 B] = 4096
#define L_XRF 151552   // x_r fp8 A-frags [4 kt][64][8] = 2048
#define L_XIF 153600   // x_imp fp8 frags = 2048
#define L_MF  155648   // m fp8 frags = 2048
#define L_RED 157696   // 16 f32
#define L_TOT 157760

__device__ __forceinline__ unsigned short f2bf(float f){
  union { float f; unsigned u; } v; v.f = f;
  unsigned r = v.u + 0x7FFFu + ((v.u >> 16) & 1u);
  return (unsigned short)(r >> 16);
}
__device__ __forceinline__ float bf2f(unsigned short u){
  union { unsigned u; float f; } v; v.u = ((unsigned)u) << 16; return v.f;
}
__device__ __forceinline__ float sigm(float v){ return 1.f/(1.f + __expf(-v)); }
__device__ __forceinline__ float tanhfast(float v){ return 2.f*sigm(2.f*v) - 1.f; }
__device__ __forceinline__ unsigned pk4(float a, float b, float c, float d){
  int v = __builtin_amdgcn_cvt_pk_fp8_f32(a, b, 0, false);
  v = __builtin_amdgcn_cvt_pk_fp8_f32(c, d, v, true);
  return (unsigned)v;
}
__device__ __forceinline__ unsigned pk2(unsigned short a, unsigned short b){
  return (unsigned)a | ((unsigned)b << 16);
}
__device__ __forceinline__ f32x4 mfma8(i64 a, i64 b, f32x4 c){
  return __builtin_amdgcn_mfma_f32_16x16x32_fp8_fp8(a, b, c, 0, 0, 0);
}
__device__ __forceinline__ f32x4 mfma16b(bf16x8 a, bf16x8 b, f32x4 c){
  return __builtin_amdgcn_mfma_f32_16x16x32_bf16(a, b, c, 0, 0, 0);
}

// ---------------- pack fp8 weight tiles ----------------
__global__ void pack_w8(const float* Whh, const float* Wih, const float* Whist,
                        const float* Wr, unsigned char* wq){
  int gt = blockIdx.x*4 + (threadIdx.x>>6);
  int lane = threadIdx.x & 63;
  if (gt >= TQ_TOT) return;
  int lr = lane & 15, lg = lane >> 4;
  const float* src; int n, k0, K; int dm = 0;
  if (gt < TQ_WIHM){ int id = gt; int kt = id & 7, gnt = id >> 3;
    n = (gnt>>4)*256 + (gnt&15)*16 + lr; k0 = kt*32 + lg*8; src = Whh; K = 256; }
  else if (gt < TQ_WIHX){ int id = gt - TQ_WIHM; int kt = id & 3, gnt = id >> 2;
    n = (gnt>>4)*256 + (gnt&15)*16 + lr; k0 = 128 + kt*32 + lg*8; src = Wih; K = 256; }
  else if (gt < TQ_HIST){ int id = gt - TQ_WIHX; int kt = id & 3, gnt = id >> 2;
    n = (gnt>>4)*256 + (gnt&15)*16 + lr; k0 = kt*32 + lg*8; src = Wih; K = 256; }
  else if (gt < TQ_WR){ int id = gt - TQ_HIST; int kt = id & 7, nt = id >> 3;
    n = nt*16 + lr; k0 = kt*32 + lg*8; src = Whist; K = 256; }
  else { int id = gt - TQ_WR; int kt = id & 3, nt = id >> 2;
    n = nt*16 + lr; k0 = kt*32 + lg*8; src = Wr; K = 128; dm = 1; }
  float f[8];
  #pragma unroll
  for (int e = 0; e < 8; ++e){
    int k = k0 + e;
    float v = src[(size_t)n*K + k];
    if (dm && n == k) v = 0.f;
    f[e] = v;
  }
  unsigned lo = pk4(f[0],f[1],f[2],f[3]), hi = pk4(f[4],f[5],f[6],f[7]);
  *(unsigned*)(wq + (size_t)gt*512 + lane*8) = lo;
  *(unsigned*)(wq + (size_t)gt*512 + lane*8 + 4) = hi;
}

// ---------------- pack bf16 tiles (prep weights) ----------------
__global__ void pack_w16(const float* Wdec, const float* Wv, unsigned short* wb){
  int gt = blockIdx.x*4 + (threadIdx.x>>6);
  int lane = threadIdx.x & 63;
  if (gt >= TB_TOT) return;
  int lr = lane & 15, lg = lane >> 4;
  const float* src; int n; int dm = 0;
  int kt;
  if (gt < TB_WV){ kt = gt & 3; n = (gt>>2)*16 + lr; src = Wdec; }
  else { int id = gt - TB_WV; kt = id & 3; n = (id>>2)*16 + lr; src = Wv; dm = 1; }
  int k0 = kt*32 + lg*8;
  u16x8 pkv;
  #pragma unroll
  for (int e = 0; e < 8; ++e){
    int k = k0 + e;
    float v = src[(size_t)n*128 + k];
    if (dm && n == k) v = 0.f;
    pkv[e] = f2bf(v);
  }
  *(u16x8*)(wb + (size_t)gt*512 + lane*8) = pkv;
}

// ---------------- per-step mask sums ----------------
__global__ void msum_kernel(const float* m, float* wsf){
  int t = blockIdx.x;
  float s = 0.f;
  for (int i = threadIdx.x; i < BQ*DD/4; i += 256){
    int b = i >> 5, c4 = (i & 31)*4;
    f32x4 v = *(const f32x4*)(m + ((size_t)b*TT + t)*DD + c4);
    s += v[0]+v[1]+v[2]+v[3];
  }
  #pragma unroll
  for (int off = 32; off >= 1; off >>= 1) s += __shfl_down(s, off);
  __shared__ float ps[4];
  if ((threadIdx.x & 63) == 0) ps[threadIdx.x >> 6] = s;
  __syncthreads();
  if (threadIdx.x == 0) wsf[WS_MSUMF + t] = ps[0] + ps[1] + ps[2] + ps[3];
}

// ---------------- final loss reduction ----------------
__global__ void loss_final(const float* wsf, float* out_loss){
  __shared__ float ps[TT];
  int t = threadIdx.x;
  float s = 0.f;
  #pragma unroll 4
  for (int b = 0; b < NBLK; ++b) s += wsf[t*NBLK + b];
  ps[t] = s / (wsf[WS_MSUMF + t] + 1e-5f);
  __syncthreads();
  if (t == 0){ float a = 0.f; for (int i = 0; i < TT; ++i) a += ps[i]; *out_loss = a; }
}

// ---------------- prep: gamma/xu + stream relayout ----------------
__global__ __launch_bounds__(NTH, 2) void prep_kernel(
    const float* __restrict__ x, const float* __restrict__ xhat,
    const float* __restrict__ m, const float* __restrict__ dly,
    const float* __restrict__ b_dec, const float* __restrict__ bv,
    const unsigned short* __restrict__ wb, unsigned* __restrict__ sa,
    float* __restrict__ out_xu)
{
  __shared__ __align__(16) char sm[16384];  // d-frag 4K | xb-frag 4K | x 4K | m 4K
  const int tid = threadIdx.x, w = tid>>6, lane = tid&63, lr = lane&15, lg = lane>>4;
  const int btile = blockIdx.x >> 3, tch = blockIdx.x & 7, b0 = btile*16;
  const int colD = w*16 + lr, colH0 = w*32 + lr;
  bf16x8 decR[2][4], wvR[4];
  #pragma unroll
  for (int s = 0; s < 2; ++s)
    #pragma unroll
    for (int kt = 0; kt < 4; ++kt)
      decR[s][kt] = *(const bf16x8*)(wb + (size_t)(TB_DEC + (w*2+s)*4 + kt)*512 + lane*8);
  #pragma unroll
  for (int kt = 0; kt < 4; ++kt)
    wvR[kt] = *(const bf16x8*)(wb + (size_t)(TB_WV + w*4 + kt)*512 + lane*8);
  const float bd0 = b_dec[colH0], bd1 = b_dec[colH0+16], bvv = bv[colD];
  const int srow = tid >> 5, c4 = (tid & 31)*4;
  const int kt_ = c4 >> 5, dl_ = ((c4 & 31) >> 3)*16 + srow, e0_ = c4 & 7;
  const size_t gbase = (size_t)(b0 + srow)*TT*DD + c4;
  const int tg0 = tch*16;

  f32x4 xv = __builtin_nontemporal_load((const f32x4*)(x    + gbase + (size_t)tg0*DD));
  f32x4 hv = __builtin_nontemporal_load((const f32x4*)(xhat + gbase + (size_t)tg0*DD));
  f32x4 mv = __builtin_nontemporal_load((const f32x4*)(m    + gbase + (size_t)tg0*DD));
  f32x4 dv = __builtin_nontemporal_load((const f32x4*)(dly  + gbase + (size_t)tg0*DD));

  for (int tt = 0; tt < 16; ++tt){
    int tg = tg0 + tt;
    u16x4 pd, pxb, px, pm;
    #pragma unroll
    for (int e = 0; e < 4; ++e){
      pd[e]  = f2bf(dv[e]);
      pxb[e] = f2bf(mv[e]*xv[e] + (1.f - mv[e])*hv[e]);
      px[e]  = f2bf(xv[e]);
      pm[e]  = f2bf(mv[e]);
    }
    *(u16x4*)(sm + 0     + kt_*1024 + dl_*16 + e0_*2) = pd;
    *(u16x4*)(sm + 4096  + kt_*1024 + dl_*16 + e0_*2) = pxb;
    *(u16x4*)(sm + 8192  + srow*256 + c4*2) = px;
    *(u16x4*)(sm + 12288 + srow*256 + c4*2) = pm;
    __syncthreads();

    // prefetch next iteration's inputs
    {
      size_t g2 = gbase + (size_t)((tt < 15) ? tg+1 : tg)*DD;
      xv = __builtin_nontemporal_load((const f32x4*)(x    + g2));
      hv = __builtin_nontemporal_load((const f32x4*)(xhat + g2));
      mv = __builtin_nontemporal_load((const f32x4*)(m    + g2));
      dv = __builtin_nontemporal_load((const f32x4*)(dly  + g2));
    }

    f32x4 ga0 = {0.f,0.f,0.f,0.f}, ga1 = {0.f,0.f,0.f,0.f}, xu4 = {0.f,0.f,0.f,0.f};
    #pragma unroll
    for (int kt = 0; kt < 4; ++kt){
      bf16x8 df  = *(const bf16x8*)(sm + 0    + kt*1024 + lane*16);
      bf16x8 xbf = *(const bf16x8*)(sm + 4096 + kt*1024 + lane*16);
      ga0 = mfma16b(df, decR[0][kt], ga0);
      ga1 = mfma16b(df, decR[1][kt], ga1);
      xu4 = mfma16b(xbf, wvR[kt], xu4);
    }
    unsigned short g8[8], xm8[8];
    float xuo[4];
    #pragma unroll
    for (int r = 0; r < 4; ++r){
      g8[r]   = f2bf(__expf(-fmaxf(ga0[r] + bd0, 0.f)));
      g8[4+r] = f2bf(__expf(-fmaxf(ga1[r] + bd1, 0.f)));
      int row = lg*4 + r;
      xm8[r]   = *(const unsigned short*)(sm + 8192  + row*256 + colD*2);
      xm8[4+r] = *(const unsigned short*)(sm + 12288 + row*256 + colD*2);
      xuo[r] = xu4[r] + bvv;
    }
    unsigned* rp = sa + (((size_t)tg*NBLK + btile)*512 + tid)*12;
    u32x4 r0 = {pk2(g8[0],g8[1]), pk2(g8[2],g8[3]), pk2(g8[4],g8[5]), pk2(g8[6],g8[7])};
    u32x4 r1 = {pk2(xm8[0],xm8[1]), pk2(xm8[2],xm8[3]), pk2(xm8[4],xm8[5]), pk2(xm8[6],xm8[7])};
    u32x4 r2 = {pk2(f2bf(xuo[0]),f2bf(xuo[1])), pk2(f2bf(xuo[2]),f2bf(xuo[3])), 0u, 0u};
    __builtin_nontemporal_store(r0, (u32x4*)rp);
    __builtin_nontemporal_store(r1, (u32x4*)(rp+4));
    __builtin_nontemporal_store(r2, (u32x4*)(rp+8));
    #pragma unroll
    for (int r = 0; r < 4; ++r)
      __builtin_nontemporal_store(xuo[r], out_xu + ((size_t)(b0 + lg*4 + r)*TT + tg)*DD + colD);
    __syncthreads();
  }
}

// ---------------- the weight-stationary recurrent scan ----------------
__global__ __launch_bounds__(NTH) __attribute__((amdgpu_waves_per_eu(2, 2)))
void scan_kernel(
    const unsigned char* __restrict__ wq, const unsigned* __restrict__ sa,
    const float* __restrict__ b_hist, const float* __restrict__ br,
    const float* __restrict__ b_ih, const float* __restrict__ b_hh,
    const float* __restrict__ conv_w, const float* __restrict__ conv_b,
    const float* __restrict__ W_out, const float* __restrict__ b_out,
    float* __restrict__ lossP,
    float* __restrict__ out_ximp, float* __restrict__ out_y,
    float* __restrict__ out_ys, float* __restrict__ out_xrs)
{
  extern __shared__ __align__(16) char lds[];
  const int tid = threadIdx.x, w = tid>>6, lane = tid&63, lr = lane&15, lg = lane>>4;
  const int b0 = blockIdx.x*16;
  const int colD = w*16 + lr, colH0 = w*32 + lr;

  // resident weight registers (fp8): Whh full + Wih_m slice
  i64 whhR[3][2][8], wihmR[3][2][4];
  #pragma unroll
  for (int g = 0; g < 3; ++g)
    #pragma unroll
    for (int s = 0; s < 2; ++s){
      #pragma unroll
      for (int kt = 0; kt < 8; ++kt)
        whhR[g][s][kt] = *(const i64*)(wq + (size_t)(TQ_WHH + ((g*16 + w*2+s)*8 + kt))*512 + lane*8);
      #pragma unroll
      for (int kt = 0; kt < 4; ++kt)
        wihmR[g][s][kt] = *(const i64*)(wq + (size_t)(TQ_WIHM + ((g*16 + w*2+s)*4 + kt))*512 + lane*8);
    }
  // LDS-resident weights: wihx + hist + wr (tiles 576..863, contiguous)
  for (int i = tid; i < 147456/16; i += NTH)
    *(u32x4*)(lds + (size_t)i*16) = *(const u32x4*)(wq + (size_t)576*512 + (size_t)i*16);

  const float bhist_v = b_hist[colD], br_v = br[colD];
  float brz[2][2], bihn[2], bhhn[2];
  #pragma unroll
  for (int s = 0; s < 2; ++s){
    int cH = colH0 + s*16;
    brz[0][s] = b_ih[cH] + b_hh[cH];
    brz[1][s] = b_ih[256+cH] + b_hh[256+cH];
    bihn[s] = b_ih[512+cH]; bhhn[s] = b_hh[512+cH];
  }
  const float cw0 = conv_w[0], cw1 = conv_w[1], cb = conv_b[0];

  const int hb0 = L_HF8 + w*512 + (lr>>3)*128 + lg*32 + (lr&7);          // + s*256 + r*8
  const int f80 = (w>>1)*512 + ((w&1)*2 + (lr>>3))*128 + lg*32 + (lr&7); // + r*8
  float* red = (float*)(lds + L_RED);

  float hs[2][4] = {{0.f,0.f,0.f,0.f},{0.f,0.f,0.f,0.f}};

  const unsigned* recp = sa + ((size_t)blockIdx.x*512 + tid)*12;
  const size_t REC_ST = (size_t)NBLK*512*12;
  u32x4 pfA = __builtin_nontemporal_load((const u32x4*)recp);
  u32x4 pfB = __builtin_nontemporal_load((const u32x4*)(recp+4));
  u32x2 pfC = __builtin_nontemporal_load((const u32x2*)(recp+8));

  #pragma unroll 1
  for (int t = 0; t < TT; ++t){
    // ---------- PH0: issue next-step stream loads; h *= gamma; stage h'/m fp8 frags ----------
    const unsigned* np = (t < TT-1) ? (recp + REC_ST) : recp;
    u32x4 nA = __builtin_nontemporal_load((const u32x4*)np);
    u32x4 nB = __builtin_nontemporal_load((const u32x4*)(np+4));
    u32x2 nC = __builtin_nontemporal_load((const u32x2*)(np+8));

    #pragma unroll
    for (int s = 0; s < 2; ++s)
      #pragma unroll
      for (int r = 0; r < 4; ++r){
        unsigned word = pfA[(s*4+r)>>1];
        float g = bf2f((unsigned short)(((s*4+r)&1) ? (word>>16) : word));
        hs[s][r] *= g;
      }
    unsigned q0 = pk4(hs[0][0], hs[0][1], hs[0][2], hs[0][3]);
    unsigned q1 = pk4(hs[1][0], hs[1][1], hs[1][2], hs[1][3]);
    #pragma unroll
    for (int r = 0; r < 4; ++r){
      *(unsigned char*)(lds + hb0 +       r*8) = (unsigned char)(q0 >> (8*r));
      *(unsigned char*)(lds + hb0 + 256 + r*8) = (unsigned char)(q1 >> (8*r));
    }
    #pragma unroll
    for (int r = 0; r < 4; ++r){
      unsigned word = pfB[2 + (r>>1)];
      unsigned short mu = (unsigned short)((r&1) ? (word>>16) : word);
      *(unsigned char*)(lds + L_MF + f80 + r*8) = mu ? 0x38 : 0x00;
    }
    __syncthreads();  // B1

    // ---------- PH1: gh + gim + xh ----------
    i64 ha[8];
    #pragma unroll
    for (int kt = 0; kt < 8; ++kt)
      ha[kt] = *(const i64*)(lds + L_HF8 + kt*512 + lane*8);
    i64 ma[4];
    #pragma unroll
    for (int kt = 0; kt < 4; ++kt) ma[kt] = *(const i64*)(lds + L_MF + kt*512 + lane*8);

    f32x4 z4 = {0.f,0.f,0.f,0.f};
    f32x4 aRZ[2][2] = {{z4,z4},{z4,z4}};
    f32x4 aNh[2] = {z4,z4}, aNi[2] = {z4,z4}, xh4 = z4;
    #pragma unroll
    for (int s = 0; s < 2; ++s)
      #pragma unroll
      for (int kt = 0; kt < 8; ++kt){
        aRZ[0][s] = mfma8(ha[kt], whhR[0][s][kt], aRZ[0][s]);
        aRZ[1][s] = mfma8(ha[kt], whhR[1][s][kt], aRZ[1][s]);
        aNh[s]    = mfma8(ha[kt], whhR[2][s][kt], aNh[s]);
      }
    #pragma unroll
    for (int kt = 0; kt < 8; ++kt)
      xh4 = mfma8(ha[kt], *(const i64*)(lds + L_HI + (w*8+kt)*512 + lane*8), xh4);
    #pragma unroll
    for (int s = 0; s < 2; ++s)
      #pragma unroll
      for (int kt = 0; kt < 4; ++kt){
        aRZ[0][s] = mfma8(ma[kt], wihmR[0][s][kt], aRZ[0][s]);
        aRZ[1][s] = mfma8(ma[kt], wihmR[1][s][kt], aRZ[1][s]);
        aNi[s]    = mfma8(ma[kt], wihmR[2][s][kt], aNi[s]);
      }
    float xv_[4], mv_[4];
    #pragma unroll
    for (int r = 0; r < 4; ++r){
      unsigned wx = pfB[r>>1];
      xv_[r] = bf2f((unsigned short)((r&1) ? (wx>>16) : wx));
      unsigned wm = pfB[2 + (r>>1)];
      mv_[r] = bf2f((unsigned short)((r&1) ? (wm>>16) : wm));
    }
    {
      float x0 = mv_[0]*xv_[0] + (1.f-mv_[0])*(xh4[0] + bhist_v);
      float x1 = mv_[1]*xv_[1] + (1.f-mv_[1])*(xh4[1] + bhist_v);
      float x2 = mv_[2]*xv_[2] + (1.f-mv_[2])*(xh4[2] + bhist_v);
      float x3 = mv_[3]*xv_[3] + (1.f-mv_[3])*(xh4[3] + bhist_v);
      unsigned p = pk4(x0, x1, x2, x3);
      #pragma unroll
      for (int r = 0; r < 4; ++r)
        *(unsigned char*)(lds + L_XRF + f80 + r*8) = (unsigned char)((p >> (8*r)) & 0xff);
    }
    __syncthreads();  // B2

    // ---------- PH2: xr, outputs, loss, x_imp ----------
    f32x4 xr4 = z4;
    #pragma unroll
    for (int kt = 0; kt < 4; ++kt)
      xr4 = mfma8(*(const i64*)(lds + L_XRF + kt*512 + lane*8),
                  *(const i64*)(lds + L_WR2 + (w*4+kt)*512 + lane*8), xr4);
    float lpart = 0.f, xi_[4];
    #pragma unroll
    for (int r = 0; r < 4; ++r){
      int row = lg*4 + r;
      size_t go = ((size_t)(b0+row)*TT + t)*DD + colD;
      float xrv = xr4[r] + br_v;
      unsigned wu = pfC[r>>1];
      float xuv = bf2f((unsigned short)((r&1) ? (wu>>16) : wu));
      __builtin_nontemporal_store(xrv, out_xrs + go);
      float xc = cw0*xuv + cw1*xrv + cb;
      lpart += fabsf(xv_[r] - xc)*mv_[r];
      xi_[r] = mv_[r]*xv_[r] + (1.f - mv_[r])*xc;
      __builtin_nontemporal_store(xi_[r], out_ximp + go);
    }
    {
      unsigned q = pk4(xi_[0], xi_[1], xi_[2], xi_[3]);
      #pragma unroll
      for (int r = 0; r < 4; ++r)
        *(unsigned char*)(lds + L_XIF + f80 + r*8) = (unsigned char)((q >> (8*r)) & 0xff);
    }
    #pragma unroll
    for (int off = 32; off >= 1; off >>= 1) lpart += __shfl_down(lpart, off);
    if (lane == 0) red[(t&1)*8 + w] = lpart;
    __syncthreads();  // B3

    // ---------- PH3: gi_x + gates + h update ----------
    i64 xia[4];
    #pragma unroll
    for (int kt = 0; kt < 4; ++kt) xia[kt] = *(const i64*)(lds + L_XIF + kt*512 + lane*8);
    #pragma unroll
    for (int s = 0; s < 2; ++s)
      #pragma unroll
      for (int kt = 0; kt < 4; ++kt){
        aRZ[0][s] = mfma8(xia[kt], *(const i64*)(lds + L_WX + ((0*16 + w*2+s)*4 + kt)*512 + lane*8), aRZ[0][s]);
        aRZ[1][s] = mfma8(xia[kt], *(const i64*)(lds + L_WX + ((1*16 + w*2+s)*4 + kt)*512 + lane*8), aRZ[1][s]);
        aNi[s]    = mfma8(xia[kt], *(const i64*)(lds + L_WX + ((2*16 + w*2+s)*4 + kt)*512 + lane*8), aNi[s]);
      }
    if (tid == 0){
      float ssum = 0.f;
      #pragma unroll
      for (int i = 0; i < 8; ++i) ssum += red[(t&1)*8 + i];
      lossP[t*NBLK + blockIdx.x] = ssum;
    }
    #pragma unroll
    for (int s = 0; s < 2; ++s)
      #pragma unroll
      for (int r = 0; r < 4; ++r){
        float rr = sigm(aRZ[0][s][r] + brz[0][s]);
        float zz = sigm(aRZ[1][s][r] + brz[1][s]);
        float hn = aNh[s][r] + bhhn[s];
        float nn = tanhfast(aNi[s][r] + bihn[s] + rr*hn);
        hs[s][r] = (1.f - zz)*nn + zz*hs[s][r];
      }
    pfA = nA; pfB = nB; pfC = nC; recp = np;
  }

  // ---------- epilogue: y = h_fin @ W_out^T + b ----------
  __syncthreads();
  float* hfin = (float*)lds;
  #pragma unroll
  for (int s = 0; s < 2; ++s)
    #pragma unroll
    for (int r = 0; r < 4; ++r)
      hfin[(lg*4+r)*HH + colH0 + s*16] = hs[s][r];
  __syncthreads();
  float* psum = (float*)(lds + 16384);
  if (tid < 256){
    int row = tid >> 4, seg = tid & 15;
    float p = 0.f;
    #pragma unroll
    for (int c = 0; c < 16; ++c) p += hfin[row*HH + seg*16 + c]*W_out[seg*16 + c];
    psum[tid] = p;
  }
  __syncthreads();
  if (tid < 16){
    float yv = b_out[0];
    #pragma unroll
    for (int i = 0; i < 16; ++i) yv += psum[tid*16 + i];
    out_y[b0 + tid] = yv;
    out_ys[b0 + tid] = sigm(yv);
  }
}

extern "C" void kernel_launch(void* const* d_in, const int* in_sizes, int n_in,
                              void* d_out, int out_size, void* d_ws, size_t ws_size,
                              hipStream_t stream){
  const float* x     = (const float*)d_in[0];
  const float* xhat  = (const float*)d_in[1];
  const float* m     = (const float*)d_in[3];
  const float* dly   = (const float*)d_in[4];
  const float* Wdec  = (const float*)d_in[5];
  const float* b_dec = (const float*)d_in[6];
  const float* Whist = (const float*)d_in[7];
  const float* b_hist= (const float*)d_in[8];
  const float* Wv    = (const float*)d_in[9];
  const float* bvv   = (const float*)d_in[10];
  const float* Wr    = (const float*)d_in[11];
  const float* brr   = (const float*)d_in[12];
  const float* convw = (const float*)d_in[13];
  const float* convb = (const float*)d_in[14];
  const float* Wih   = (const float*)d_in[15];
  const float* Whh   = (const float*)d_in[16];
  const float* b_ih  = (const float*)d_in[17];
  const float* b_hh  = (const float*)d_in[18];
  const float* W_out = (const float*)d_in[19];
  const float* b_out = (const float*)d_in[20];

  float* wsf = (float*)d_ws;                    // [0..8191] lossP[t][blk], [8192..8319] msums
  unsigned char* wq = (unsigned char*)d_ws + WS_WQ8;
  unsigned short* wb = (unsigned short*)((char*)d_ws + WS_WB16);
  unsigned* sa = (unsigned*)((char*)d_ws + WS_SA);

  float* out = (float*)d_out;
  size_t btd = (size_t)BQ*TT*DD;
  float* out_ximp = out;
  float* out_y    = out + btd;
  float* out_ys   = out_y + BQ;
  float* out_loss = out_ys + BQ;
  float* out_xu   = out_loss + 1;
  float* out_xrs  = out_xu + btd;

  (void)hipFuncSetAttribute((const void*)scan_kernel,
                            hipFuncAttributeMaxDynamicSharedMemorySize, L_TOT);

  pack_w8<<<TQ_TOT/4, 256, 0, stream>>>(Whh, Wih, Whist, Wr, wq);
  pack_w16<<<TB_TOT/4, 256, 0, stream>>>(Wdec, Wv, wb);
  msum_kernel<<<TT, 256, 0, stream>>>(m, wsf);
  prep_kernel<<<512, NTH, 0, stream>>>(x, xhat, m, dly, b_dec, bvv, wb, sa, out_xu);
  scan_kernel<<<NBLK, NTH, L_TOT, stream>>>(wq, sa, b_hist, brr, b_ih, b_hh,
      convw, convb, W_out, b_out, wsf,
      out_ximp, out_y, out_ys, out_xrs);
  loss_final<<<1, TT, 0, stream>>>(wsf, out_loss);
}

// Round 7
// 625.192 us; speedup vs baseline: 7.2759x; 1.5538x over previous
//
#include <hip/hip_runtime.h>
#include <math.h>

#define BQ 1024
#define TT 128
#define DD 128
#define HH 256
#define NW 8
#define NTH 512
#define NBLK 64

typedef float f32x4 __attribute__((ext_vector_type(4)));
typedef __bf16 bf16x8 __attribute__((ext_vector_type(8)));
typedef unsigned short u16x4 __attribute__((ext_vector_type(4)));
typedef unsigned short u16x8 __attribute__((ext_vector_type(8)));
typedef unsigned int u32x4 __attribute__((ext_vector_type(4)));
typedef unsigned int u32x2 __attribute__((ext_vector_type(2)));
typedef long long i64;

// ---- ws layout (bytes) ----
#define WS_MSUMF 8192        // float index of msums (byte 32768)
#define WS_WQ8   40960       // 864 fp8 tiles * 512 B -> ends 483328
#define WS_WB16  487424      // 96 bf16 tiles * 1024 B -> ends 585728
#define WS_SA1   589824      // saA: [t][blk][tid] * 16 B = 67108864
#define WS_SA2   67698688    // saB: [t][blk][tid] * 24 B = 100663296 -> ~168.4MB

// fp8 tile map in wq (tile = 512 B):
//  [0,384):   Whh   [(g*16+nt8)*8+kt]
//  [384,576): Wih_x [(g*16+nt8)*4+kt]  (cols 0..127)
//  [576,640): Whist [nt*8+kt]
//  [640,672): Wr    [nt*4+kt] diag0
//  [672,864): Wih_m [(g*16+nt8)*4+kt]  (cols 128..255)
#define TQ_TOT  864

// bf16 tiles (prep1 weights)
#define TB_DEC 0
#define TB_WV  64
#define TB_TOT 96

// ---- scan LDS map (bytes) ----
#define L_WX  0        // wihx 192*512 = 98304
#define L_HI  98304    // hist 64*512 = 32768
#define L_WR  131072   // wr 32*512 = 16384
#define L_HF8 147456   // h' fp8 A-frags [8 kt][64][8] = 4096
#define L_XRF 151552   // x_r fp8 frags = 2048
#define L_XIF 153600   // x_imp fp8 frags = 2048
#define L_RED 155648   // 16 f32
#define L_TOT 155712

__device__ __forceinline__ unsigned short f2bf(float f){
  union { float f; unsigned u; } v; v.f = f;
  unsigned r = v.u + 0x7FFFu + ((v.u >> 16) & 1u);
  return (unsigned short)(r >> 16);
}
__device__ __forceinline__ float sigm(float v){ return 1.f/(1.f + __expf(-v)); }
__device__ __forceinline__ float tanhfast(float v){ return 2.f*sigm(2.f*v) - 1.f; }
__device__ __forceinline__ unsigned pk4(float a, float b, float c, float d){
  int v = __builtin_amdgcn_cvt_pk_fp8_f32(a, b, 0, false);
  v = __builtin_amdgcn_cvt_pk_fp8_f32(c, d, v, true);
  return (unsigned)v;
}
__device__ __forceinline__ f32x4 upk4(unsigned w){
  f32x4 r;
  r[0] = __builtin_amdgcn_cvt_f32_fp8((int)w, 0);
  r[1] = __builtin_amdgcn_cvt_f32_fp8((int)w, 1);
  r[2] = __builtin_amdgcn_cvt_f32_fp8((int)w, 2);
  r[3] = __builtin_amdgcn_cvt_f32_fp8((int)w, 3);
  return r;
}
__device__ __forceinline__ f32x4 mfma8(i64 a, i64 b, f32x4 c){
  return __builtin_amdgcn_mfma_f32_16x16x32_fp8_fp8(a, b, c, 0, 0, 0);
}
__device__ __forceinline__ f32x4 mfma16b(bf16x8 a, bf16x8 b, f32x4 c){
  return __builtin_amdgcn_mfma_f32_16x16x32_bf16(a, b, c, 0, 0, 0);
}

// ---------------- pack fp8 weight tiles ----------------
__global__ void pack_w8(const float* Whh, const float* Wih, const float* Whist,
                        const float* Wr, unsigned char* wq){
  int gt = blockIdx.x*4 + (threadIdx.x>>6);
  int lane = threadIdx.x & 63;
  if (gt >= TQ_TOT) return;
  int lr = lane & 15, lg = lane >> 4;
  const float* src; int n, k0, K; int dm = 0;
  if (gt < 384){ int kt = gt & 7, gnt = gt >> 3;
    n = (gnt>>4)*256 + (gnt&15)*16 + lr; k0 = kt*32 + lg*8; src = Whh; K = 256; }
  else if (gt < 576){ int id = gt-384; int kt = id & 3, gnt = id >> 2;
    n = (gnt>>4)*256 + (gnt&15)*16 + lr; k0 = kt*32 + lg*8; src = Wih; K = 256; }
  else if (gt < 640){ int id = gt-576; int kt = id & 7, nt = id >> 3;
    n = nt*16 + lr; k0 = kt*32 + lg*8; src = Whist; K = 256; }
  else if (gt < 672){ int id = gt-640; int kt = id & 3, nt = id >> 2;
    n = nt*16 + lr; k0 = kt*32 + lg*8; src = Wr; K = 128; dm = 1; }
  else { int id = gt-672; int kt = id & 3, gnt = id >> 2;
    n = (gnt>>4)*256 + (gnt&15)*16 + lr; k0 = 128 + kt*32 + lg*8; src = Wih; K = 256; }
  float f[8];
  #pragma unroll
  for (int e = 0; e < 8; ++e){
    int k = k0 + e;
    float v = src[(size_t)n*K + k];
    if (dm && n == k) v = 0.f;
    f[e] = v;
  }
  unsigned lo = pk4(f[0],f[1],f[2],f[3]), hi = pk4(f[4],f[5],f[6],f[7]);
  *(unsigned*)(wq + (size_t)gt*512 + lane*8) = lo;
  *(unsigned*)(wq + (size_t)gt*512 + lane*8 + 4) = hi;
}

// ---------------- pack bf16 tiles (prep1 weights) ----------------
__global__ void pack_w16(const float* Wdec, const float* Wv, unsigned short* wb){
  int gt = blockIdx.x*4 + (threadIdx.x>>6);
  int lane = threadIdx.x & 63;
  if (gt >= TB_TOT) return;
  int lr = lane & 15, lg = lane >> 4;
  const float* src; int n; int dm = 0; int kt;
  if (gt < TB_WV){ kt = gt & 3; n = (gt>>2)*16 + lr; src = Wdec; }
  else { int id = gt - TB_WV; kt = id & 3; n = (id>>2)*16 + lr; src = Wv; dm = 1; }
  int k0 = kt*32 + lg*8;
  u16x8 pkv;
  #pragma unroll
  for (int e = 0; e < 8; ++e){
    int k = k0 + e;
    float v = src[(size_t)n*128 + k];
    if (dm && n == k) v = 0.f;
    pkv[e] = f2bf(v);
  }
  *(u16x8*)(wb + (size_t)gt*512 + lane*8) = pkv;
}

// ---------------- per-step mask sums ----------------
__global__ void msum_kernel(const float* m, float* wsf){
  int t = blockIdx.x;
  float s = 0.f;
  for (int i = threadIdx.x; i < BQ*DD/4; i += 256){
    int b = i >> 5, c4 = (i & 31)*4;
    f32x4 v = *(const f32x4*)(m + ((size_t)b*TT + t)*DD + c4);
    s += v[0]+v[1]+v[2]+v[3];
  }
  #pragma unroll
  for (int off = 32; off >= 1; off >>= 1) s += __shfl_down(s, off);
  __shared__ float ps[4];
  if ((threadIdx.x & 63) == 0) ps[threadIdx.x >> 6] = s;
  __syncthreads();
  if (threadIdx.x == 0) wsf[WS_MSUMF + t] = ps[0] + ps[1] + ps[2] + ps[3];
}

// ---------------- final loss reduction ----------------
__global__ void loss_final(const float* wsf, float* out_loss){
  __shared__ float ps[TT];
  int t = threadIdx.x;
  float s = 0.f;
  #pragma unroll 4
  for (int b = 0; b < NBLK; ++b) s += wsf[t*NBLK + b];
  ps[t] = s / (wsf[WS_MSUMF + t] + 1e-5f);
  __syncthreads();
  if (t == 0){ float a = 0.f; for (int i = 0; i < TT; ++i) a += ps[i]; *out_loss = a; }
}

// ---------------- prep1: gamma/xu/mask stream + out_xu ----------------
__global__ __launch_bounds__(NTH, 2) void prep1_kernel(
    const float* __restrict__ x, const float* __restrict__ xhat,
    const float* __restrict__ m, const float* __restrict__ dly,
    const float* __restrict__ b_dec, const float* __restrict__ bv,
    const unsigned short* __restrict__ wb, unsigned* __restrict__ saA,
    float* __restrict__ out_xu)
{
  __shared__ __align__(16) char sm[12288];  // d-frag 4K | xb-frag 4K | m row-major 4K
  const int tid = threadIdx.x, w = tid>>6, lane = tid&63, lr = lane&15, lg = lane>>4;
  const int btile = blockIdx.x >> 4, tch = blockIdx.x & 15, b0 = btile*16;
  const int tg0 = tch*8;
  const int colD = w*16 + lr, colH0 = w*32 + lr;
  bf16x8 decR[2][4], wvR[4];
  #pragma unroll
  for (int s = 0; s < 2; ++s)
    #pragma unroll
    for (int kt = 0; kt < 4; ++kt)
      decR[s][kt] = *(const bf16x8*)(wb + (size_t)(TB_DEC + (w*2+s)*4 + kt)*512 + lane*8);
  #pragma unroll
  for (int kt = 0; kt < 4; ++kt)
    wvR[kt] = *(const bf16x8*)(wb + (size_t)(TB_WV + w*4 + kt)*512 + lane*8);
  const float bd0 = b_dec[colH0], bd1 = b_dec[colH0+16], bvv = bv[colD];
  const int srow = tid >> 5, c4 = (tid & 31)*4;
  const int kt_ = c4 >> 5, dl_ = ((c4 & 31) >> 3)*16 + srow, e0_ = c4 & 7;
  const size_t gbase = (size_t)(b0 + srow)*TT*DD + c4;

  f32x4 xv = *(const f32x4*)(x    + gbase + (size_t)tg0*DD);
  f32x4 hv = *(const f32x4*)(xhat + gbase + (size_t)tg0*DD);
  f32x4 mv = *(const f32x4*)(m    + gbase + (size_t)tg0*DD);
  f32x4 dv = *(const f32x4*)(dly  + gbase + (size_t)tg0*DD);

  for (int tt = 0; tt < 8; ++tt){
    int tg = tg0 + tt;
    u16x4 pd, pxb, pm;
    #pragma unroll
    for (int e = 0; e < 4; ++e){
      pd[e]  = f2bf(dv[e]);
      pxb[e] = f2bf(mv[e]*xv[e] + (1.f - mv[e])*hv[e]);
      pm[e]  = f2bf(mv[e]);
    }
    *(u16x4*)(sm + 0    + kt_*1024 + dl_*16 + e0_*2) = pd;
    *(u16x4*)(sm + 4096 + kt_*1024 + dl_*16 + e0_*2) = pxb;
    *(u16x4*)(sm + 8192 + srow*256 + c4*2) = pm;
    __syncthreads();

    {
      size_t g2 = gbase + (size_t)((tt < 7) ? tg+1 : tg)*DD;
      xv = *(const f32x4*)(x + g2);
      hv = *(const f32x4*)(xhat + g2);
      mv = *(const f32x4*)(m + g2);
      dv = *(const f32x4*)(dly + g2);
    }

    f32x4 ga0 = {0.f,0.f,0.f,0.f}, ga1 = {0.f,0.f,0.f,0.f}, xu4 = {0.f,0.f,0.f,0.f};
    #pragma unroll
    for (int kt = 0; kt < 4; ++kt){
      bf16x8 df  = *(const bf16x8*)(sm + 0    + kt*1024 + lane*16);
      bf16x8 xbf = *(const bf16x8*)(sm + 4096 + kt*1024 + lane*16);
      ga0 = mfma16b(df, decR[0][kt], ga0);
      ga1 = mfma16b(df, decR[1][kt], ga1);
      xu4 = mfma16b(xbf, wvR[kt], xu4);
    }
    float g0[4], g1[4], xuo[4];
    unsigned mask = 0;
    #pragma unroll
    for (int r = 0; r < 4; ++r){
      g0[r] = __expf(-fmaxf(ga0[r] + bd0, 0.f));
      g1[r] = __expf(-fmaxf(ga1[r] + bd1, 0.f));
      xuo[r] = xu4[r] + bvv;
      int row = lg*4 + r;
      unsigned short mu = *(const unsigned short*)(sm + 8192 + row*256 + colD*2);
      mask |= (mu ? 1u : 0u) << r;
    }
    u32x4 rec = {pk4(g0[0],g0[1],g0[2],g0[3]), pk4(g1[0],g1[1],g1[2],g1[3]),
                 pk4(xuo[0],xuo[1],xuo[2],xuo[3]), mask};
    __builtin_nontemporal_store(rec,
        (u32x4*)(saA + (((size_t)tg*NBLK + btile)*512 + tid)*4));
    #pragma unroll
    for (int r = 0; r < 4; ++r)
      __builtin_nontemporal_store(xuo[r], out_xu + ((size_t)(b0 + lg*4 + r)*TT + tg)*DD + colD);
    __syncthreads();
  }
}

// ---------------- prep2: gim = m @ Wihm^T + biases (fp8 stream) ----------------
__global__ __launch_bounds__(NTH, 2) void prep2_kernel(
    const float* __restrict__ m, const float* __restrict__ b_ih,
    const float* __restrict__ b_hh, const unsigned char* __restrict__ wq,
    unsigned* __restrict__ saB)
{
  __shared__ __align__(16) char sm[2048];  // m fp8 A-frags [4 kt][64][8]
  const int tid = threadIdx.x, w = tid>>6, lane = tid&63, lr = lane&15, lg = lane>>4;
  const int btile = blockIdx.x >> 4, tch = blockIdx.x & 15, b0 = btile*16;
  const int tg0 = tch*8;
  i64 wihmR[6][4];
  float bfold[6];
  #pragma unroll
  for (int g = 0; g < 3; ++g)
    #pragma unroll
    for (int s = 0; s < 2; ++s){
      int j = g*2 + s;
      #pragma unroll
      for (int kt = 0; kt < 4; ++kt)
        wihmR[j][kt] = *(const i64*)(wq + (size_t)(672 + (g*16 + w*2+s)*4 + kt)*512 + lane*8);
      int n = g*256 + w*32 + s*16 + lr;
      bfold[j] = b_ih[n] + ((g < 2) ? b_hh[n] : 0.f);
    }
  const int srow = tid >> 5, c4 = (tid & 31)*4;
  const int kt_ = c4 >> 5, lg2 = (c4 & 31) >> 3, e0_ = c4 & 7;
  const size_t gbase = (size_t)(b0 + srow)*TT*DD + c4;

  for (int tt = 0; tt < 8; ++tt){
    int tg = tg0 + tt;
    f32x4 mv = *(const f32x4*)(m + gbase + (size_t)tg*DD);
    unsigned wbyte = 0;
    #pragma unroll
    for (int e = 0; e < 4; ++e) wbyte |= (mv[e] > 0.5f ? 0x38u : 0u) << (8*e);
    *(unsigned*)(sm + kt_*512 + (lg2*16 + srow)*8 + e0_) = wbyte;
    __syncthreads();

    i64 ma[4];
    #pragma unroll
    for (int kt = 0; kt < 4; ++kt) ma[kt] = *(const i64*)(sm + kt*512 + lane*8);
    f32x4 z4 = {0.f,0.f,0.f,0.f};
    f32x4 acc[6] = {z4,z4,z4,z4,z4,z4};
    #pragma unroll
    for (int j = 0; j < 6; ++j)
      #pragma unroll
      for (int kt = 0; kt < 4; ++kt)
        acc[j] = mfma8(ma[kt], wihmR[j][kt], acc[j]);
    unsigned wd[6];
    #pragma unroll
    for (int j = 0; j < 6; ++j)
      wd[j] = pk4(acc[j][0]+bfold[j], acc[j][1]+bfold[j], acc[j][2]+bfold[j], acc[j][3]+bfold[j]);
    unsigned* rp = saB + (((size_t)tg*NBLK + btile)*512 + tid)*6;
    u32x2 p0 = {wd[0], wd[1]}, p1 = {wd[2], wd[3]}, p2 = {wd[4], wd[5]};
    __builtin_nontemporal_store(p0, (u32x2*)rp);
    __builtin_nontemporal_store(p1, (u32x2*)(rp+2));
    __builtin_nontemporal_store(p2, (u32x2*)(rp+4));
    __syncthreads();
  }
}

// ---------------- the weight-stationary recurrent scan ----------------
__global__ __launch_bounds__(NTH) __attribute__((amdgpu_waves_per_eu(2, 2)))
void scan_kernel(
    const unsigned char* __restrict__ wq, const unsigned* __restrict__ saA,
    const unsigned* __restrict__ saB, const float* __restrict__ x,
    const float* __restrict__ b_hist, const float* __restrict__ br,
    const float* __restrict__ b_hh,
    const float* __restrict__ conv_w, const float* __restrict__ conv_b,
    const float* __restrict__ W_out, const float* __restrict__ b_out,
    float* __restrict__ lossP,
    float* __restrict__ out_ximp, float* __restrict__ out_y,
    float* __restrict__ out_ys, float* __restrict__ out_xrs)
{
  extern __shared__ __align__(16) char lds[];
  const int tid = threadIdx.x, w = tid>>6, lane = tid&63, lr = lane&15, lg = lane>>4;
  const int b0 = blockIdx.x*16;
  const int colD = w*16 + lr, colH0 = w*32 + lr;

  // register-resident Whh (fp8): 48 i64 = 96 VGPR/AGPR
  i64 whhR[3][2][8];
  #pragma unroll
  for (int g = 0; g < 3; ++g)
    #pragma unroll
    for (int s = 0; s < 2; ++s)
      #pragma unroll
      for (int kt = 0; kt < 8; ++kt)
        whhR[g][s][kt] = *(const i64*)(wq + (size_t)((g*16 + w*2+s)*8 + kt)*512 + lane*8);
  // LDS weights: wihx(192t) + hist(64t) + wr(32t) = tiles [384,672)
  for (int i = tid; i < 9216; i += NTH)
    *(u32x4*)(lds + (size_t)i*16) = *(const u32x4*)(wq + (size_t)384*512 + (size_t)i*16);

  const float bhist_v = b_hist[colD], br_v = br[colD];
  const float bhhn0 = b_hh[512 + colH0], bhhn1 = b_hh[512 + colH0 + 16];
  const float cw0 = conv_w[0], cw1 = conv_w[1], cb = conv_b[0];

  const int hb0 = L_HF8 + w*512 + (lr>>3)*128 + lg*32 + (lr&7);           // + s*256 + r*8
  const int f80 = (w>>1)*512 + ((w&1)*2 + (lr>>3))*128 + lg*32 + (lr&7);  // + r*8
  float* red = (float*)(lds + L_RED);

  float hs[2][4] = {{0.f,0.f,0.f,0.f},{0.f,0.f,0.f,0.f}};

  const unsigned* rpa = saA + ((size_t)blockIdx.x*512 + tid)*4;
  const unsigned* rpb = saB + ((size_t)blockIdx.x*512 + tid)*6;
  const size_t STA = (size_t)NBLK*512*4, STB = (size_t)NBLK*512*6;
  const float* xb = x + (size_t)(b0 + lg*4)*TT*DD + colD;

  u32x4 pfA = __builtin_nontemporal_load((const u32x4*)rpa);
  u32x2 pfB0 = __builtin_nontemporal_load((const u32x2*)rpb);
  u32x2 pfB1 = __builtin_nontemporal_load((const u32x2*)(rpb+2));
  u32x2 pfB2 = __builtin_nontemporal_load((const u32x2*)(rpb+4));
  float xc_[4];
  #pragma unroll
  for (int r = 0; r < 4; ++r) xc_[r] = xb[(size_t)r*TT*DD];

  #pragma unroll 1
  for (int t = 0; t < TT; ++t){
    // ---------- PH0: next-step loads; h *= gamma; stage h' fp8 frags ----------
    const unsigned* npa = (t < TT-1) ? (rpa + STA) : rpa;
    const unsigned* npb = (t < TT-1) ? (rpb + STB) : rpb;
    int tn = (t < TT-1) ? t+1 : t;
    u32x4 nA = __builtin_nontemporal_load((const u32x4*)npa);
    u32x2 nB0 = __builtin_nontemporal_load((const u32x2*)npb);
    u32x2 nB1 = __builtin_nontemporal_load((const u32x2*)(npb+2));
    u32x2 nB2 = __builtin_nontemporal_load((const u32x2*)(npb+4));
    float xn_[4];
    #pragma unroll
    for (int r = 0; r < 4; ++r) xn_[r] = xb[(size_t)r*TT*DD + (size_t)tn*DD];

    {
      f32x4 gA0 = upk4(pfA[0]), gA1 = upk4(pfA[1]);
      #pragma unroll
      for (int r = 0; r < 4; ++r){
        hs[0][r] *= gA0[r];
        hs[1][r] *= gA1[r];
      }
    }
    unsigned q0 = pk4(hs[0][0], hs[0][1], hs[0][2], hs[0][3]);
    unsigned q1 = pk4(hs[1][0], hs[1][1], hs[1][2], hs[1][3]);
    #pragma unroll
    for (int r = 0; r < 4; ++r){
      *(unsigned char*)(lds + hb0 +       r*8) = (unsigned char)(q0 >> (8*r));
      *(unsigned char*)(lds + hb0 + 256 + r*8) = (unsigned char)(q1 >> (8*r));
    }
    __syncthreads();  // B1

    // ---------- PH1: gh (whh regs) + xh (hist LDS); x_r -> XRF ----------
    i64 ha[8];
    #pragma unroll
    for (int kt = 0; kt < 8; ++kt)
      ha[kt] = *(const i64*)(lds + L_HF8 + kt*512 + lane*8);
    f32x4 z4 = {0.f,0.f,0.f,0.f};
    f32x4 aRZ[2][2] = {{z4,z4},{z4,z4}};
    f32x4 aNh[2] = {z4,z4}, aNi[2] = {z4,z4}, xh4 = z4;
    #pragma unroll
    for (int s = 0; s < 2; ++s)
      #pragma unroll
      for (int kt = 0; kt < 8; ++kt){
        aRZ[0][s] = mfma8(ha[kt], whhR[0][s][kt], aRZ[0][s]);
        aRZ[1][s] = mfma8(ha[kt], whhR[1][s][kt], aRZ[1][s]);
        aNh[s]    = mfma8(ha[kt], whhR[2][s][kt], aNh[s]);
      }
    #pragma unroll
    for (int kt = 0; kt < 8; ++kt)
      xh4 = mfma8(ha[kt], *(const i64*)(lds + L_HI + (w*8+kt)*512 + lane*8), xh4);
    {
      unsigned mk = pfA[3];
      float x0 = (mk & 1u) ? xc_[0] : (xh4[0] + bhist_v);
      float x1 = (mk & 2u) ? xc_[1] : (xh4[1] + bhist_v);
      float x2 = (mk & 4u) ? xc_[2] : (xh4[2] + bhist_v);
      float x3 = (mk & 8u) ? xc_[3] : (xh4[3] + bhist_v);
      unsigned p = pk4(x0, x1, x2, x3);
      #pragma unroll
      for (int r = 0; r < 4; ++r)
        *(unsigned char*)(lds + L_XRF + f80 + r*8) = (unsigned char)((p >> (8*r)) & 0xff);
    }
    __syncthreads();  // B2

    // ---------- PH2: xr (wr LDS); outputs; loss; x_imp -> XIF ----------
    f32x4 xr4 = z4;
    #pragma unroll
    for (int kt = 0; kt < 4; ++kt)
      xr4 = mfma8(*(const i64*)(lds + L_XRF + kt*512 + lane*8),
                  *(const i64*)(lds + L_WR + (w*4+kt)*512 + lane*8), xr4);
    float lpart = 0.f, xi_[4];
    unsigned mk = pfA[3];
    f32x4 xu4v = upk4(pfA[2]);
    #pragma unroll
    for (int r = 0; r < 4; ++r){
      int row = lg*4 + r;
      size_t go = ((size_t)(b0+row)*TT + t)*DD + colD;
      float xrv = xr4[r] + br_v;
      float xuv = xu4v[r];
      __builtin_nontemporal_store(xrv, out_xrs + go);
      float xc = cw0*xuv + cw1*xrv + cb;
      bool mb = (mk >> r) & 1u;
      lpart += mb ? fabsf(xc_[r] - xc) : 0.f;
      xi_[r] = mb ? xc_[r] : xc;
      __builtin_nontemporal_store(xi_[r], out_ximp + go);
    }
    {
      unsigned q = pk4(xi_[0], xi_[1], xi_[2], xi_[3]);
      #pragma unroll
      for (int r = 0; r < 4; ++r)
        *(unsigned char*)(lds + L_XIF + f80 + r*8) = (unsigned char)((q >> (8*r)) & 0xff);
    }
    #pragma unroll
    for (int off = 32; off >= 1; off >>= 1) lpart += __shfl_down(lpart, off);
    if (lane == 0) red[w] = lpart;
    __syncthreads();  // B3

    // ---------- PH3: gi_x (wihx LDS) + gates + h update ----------
    i64 xia[4];
    #pragma unroll
    for (int kt = 0; kt < 4; ++kt) xia[kt] = *(const i64*)(lds + L_XIF + kt*512 + lane*8);
    #pragma unroll
    for (int s = 0; s < 2; ++s)
      #pragma unroll
      for (int kt = 0; kt < 4; ++kt){
        aRZ[0][s] = mfma8(xia[kt], *(const i64*)(lds + L_WX + ((0*16 + w*2+s)*4 + kt)*512 + lane*8), aRZ[0][s]);
        aRZ[1][s] = mfma8(xia[kt], *(const i64*)(lds + L_WX + ((1*16 + w*2+s)*4 + kt)*512 + lane*8), aRZ[1][s]);
        aNi[s]    = mfma8(xia[kt], *(const i64*)(lds + L_WX + ((2*16 + w*2+s)*4 + kt)*512 + lane*8), aNi[s]);
      }
    if (tid == 0){
      float ssum = 0.f;
      #pragma unroll
      for (int i = 0; i < 8; ++i) ssum += red[i];
      lossP[t*NBLK + blockIdx.x] = ssum;
    }
    {
      f32x4 gR0 = upk4(pfB0[0]), gR1 = upk4(pfB0[1]);
      f32x4 gZ0 = upk4(pfB1[0]), gZ1 = upk4(pfB1[1]);
      f32x4 gN0 = upk4(pfB2[0]), gN1 = upk4(pfB2[1]);
      #pragma unroll
      for (int r = 0; r < 4; ++r){
        float rr0 = sigm(aRZ[0][0][r] + gR0[r]);
        float zz0 = sigm(aRZ[1][0][r] + gZ0[r]);
        float nn0 = tanhfast(aNi[0][r] + gN0[r] + rr0*(aNh[0][r] + bhhn0));
        hs[0][r] = (1.f - zz0)*nn0 + zz0*hs[0][r];
        float rr1 = sigm(aRZ[0][1][r] + gR1[r]);
        float zz1 = sigm(aRZ[1][1][r] + gZ1[r]);
        float nn1 = tanhfast(aNi[1][r] + gN1[r] + rr1*(aNh[1][r] + bhhn1));
        hs[1][r] = (1.f - zz1)*nn1 + zz1*hs[1][r];
      }
    }
    pfA = nA; pfB0 = nB0; pfB1 = nB1; pfB2 = nB2;
    xc_[0] = xn_[0]; xc_[1] = xn_[1]; xc_[2] = xn_[2]; xc_[3] = xn_[3];
    rpa = npa; rpb = npb;
  }

  // ---------- epilogue: y = h_fin @ W_out^T + b ----------
  __syncthreads();
  float* hfin = (float*)lds;
  #pragma unroll
  for (int s = 0; s < 2; ++s)
    #pragma unroll
    for (int r = 0; r < 4; ++r)
      hfin[(lg*4+r)*HH + colH0 + s*16] = hs[s][r];
  __syncthreads();
  float* psum = (float*)(lds + 16384);
  if (tid < 256){
    int row = tid >> 4, seg = tid & 15;
    float p = 0.f;
    #pragma unroll
    for (int c = 0; c < 16; ++c) p += hfin[row*HH + seg*16 + c]*W_out[seg*16 + c];
    psum[tid] = p;
  }
  __syncthreads();
  if (tid < 16){
    float yv = b_out[0];
    #pragma unroll
    for (int i = 0; i < 16; ++i) yv += psum[tid*16 + i];
    out_y[b0 + tid] = yv;
    out_ys[b0 + tid] = sigm(yv);
  }
}

extern "C" void kernel_launch(void* const* d_in, const int* in_sizes, int n_in,
                              void* d_out, int out_size, void* d_ws, size_t ws_size,
                              hipStream_t stream){
  const float* x     = (const float*)d_in[0];
  const float* xhat  = (const float*)d_in[1];
  const float* m     = (const float*)d_in[3];
  const float* dly   = (const float*)d_in[4];
  const float* Wdec  = (const float*)d_in[5];
  const float* b_dec = (const float*)d_in[6];
  const float* Whist = (const float*)d_in[7];
  const float* b_hist= (const float*)d_in[8];
  const float* Wv    = (const float*)d_in[9];
  const float* bvv   = (const float*)d_in[10];
  const float* Wr    = (const float*)d_in[11];
  const float* brr   = (const float*)d_in[12];
  const float* convw = (const float*)d_in[13];
  const float* convb = (const float*)d_in[14];
  const float* Wih   = (const float*)d_in[15];
  const float* Whh   = (const float*)d_in[16];
  const float* b_ih  = (const float*)d_in[17];
  const float* b_hh  = (const float*)d_in[18];
  const float* W_out = (const float*)d_in[19];
  const float* b_out = (const float*)d_in[20];

  float* wsf = (float*)d_ws;
  unsigned char* wq = (unsigned char*)d_ws + WS_WQ8;
  unsigned short* wb = (unsigned short*)((char*)d_ws + WS_WB16);
  unsigned* saA = (unsigned*)((char*)d_ws + WS_SA1);
  unsigned* saB = (unsigned*)((char*)d_ws + WS_SA2);

  float* out = (float*)d_out;
  size_t btd = (size_t)BQ*TT*DD;
  float* out_ximp = out;
  float* out_y    = out + btd;
  float* out_ys   = out_y + BQ;
  float* out_loss = out_ys + BQ;
  float* out_xu   = out_loss + 1;
  float* out_xrs  = out_xu + btd;

  (void)hipFuncSetAttribute((const void*)scan_kernel,
                            hipFuncAttributeMaxDynamicSharedMemorySize, L_TOT);

  pack_w8<<<TQ_TOT/4, 256, 0, stream>>>(Whh, Wih, Whist, Wr, wq);
  pack_w16<<<TB_TOT/4, 256, 0, stream>>>(Wdec, Wv, wb);
  msum_kernel<<<TT, 256, 0, stream>>>(m, wsf);
  prep1_kernel<<<1024, NTH, 0, stream>>>(x, xhat, m, dly, b_dec, bvv, wb, saA, out_xu);
  prep2_kernel<<<1024, NTH, 0, stream>>>(m, b_ih, b_hh, wq, saB);
  scan_kernel<<<NBLK, NTH, L_TOT, stream>>>(wq, saA, saB, x, b_hist, brr, b_hh,
      convw, convb, W_out, b_out, wsf,
      out_ximp, out_y, out_ys, out_xrs);
  loss_final<<<1, TT, 0, stream>>>(wsf, out_loss);
}